// Round 1
// baseline (605.086 us; speedup 1.0000x reference)
//
#include <hip/hip_runtime.h>

typedef unsigned short u16;
typedef __attribute__((ext_vector_type(8))) __bf16 bf16x8;
typedef __attribute__((ext_vector_type(8))) unsigned short u16x8;
typedef __attribute__((ext_vector_type(4))) unsigned short u16x4;
typedef __attribute__((ext_vector_type(4))) float f32x4;

#define BM 256
#define BN 256
#define BK 32   // K-step per LDS buffer; double-buffered

__device__ __forceinline__ float bf2f(u16 x) {
  union { unsigned int u; float f; } un;
  un.u = ((unsigned int)x) << 16;
  return un.f;
}

__device__ __forceinline__ u16 f2bf(float f) {
  union { float f; unsigned int u; } un;
  un.f = f;
  unsigned int r = un.u + 0x7fffu + ((un.u >> 16) & 1u);
  return (u16)(r >> 16);
}

__device__ __forceinline__ void cstore(u16* p, float v)   { *p = f2bf(v); }
__device__ __forceinline__ void cstore(float* p, float v) { *p = v; }

// async global->LDS, 16B per lane; lds dst is wave-uniform base (HW adds lane*16B)
__device__ __forceinline__ void async_ld16(const u16* g, u16* l) {
  __builtin_amdgcn_global_load_lds(
      (const __attribute__((address_space(1))) unsigned int*)g,
      (__attribute__((address_space(3))) unsigned int*)l, 16, 0, 0);
}

__device__ __forceinline__ bf16x8 ldfrag(const u16* p) {
  union { u16x8 u; bf16x8 b; } c;
  c.u = *(const u16x8*)p;
  return c.b;
}

// ---------------- fp32 -> bf16 elementwise (x), 4 elems/thread ----------------
__global__ __launch_bounds__(256)
void f32_to_bf16(const float* __restrict__ s, u16* __restrict__ d)
{
  const int i = blockIdx.x * 256 + threadIdx.x;
  const float4 v = ((const float4*)s)[i];
  u16x4 o;
  o.x = f2bf(v.x); o.y = f2bf(v.y); o.z = f2bf(v.z); o.w = f2bf(v.w);
  ((u16x4*)d)[i] = o;
}

// ---------------- fp32 [R][CC] -> bf16 transposed [CC][R] ----------------
__global__ __launch_bounds__(256)
void transpose_f2b(const float* __restrict__ src, int sld,
                   u16* __restrict__ dst, int dld)
{
  __shared__ float tile[32][33];
  const int c0 = blockIdx.x * 32;
  const int r0 = blockIdx.y * 32;
  const int tx = threadIdx.x;   // 0..31
  const int ty = threadIdx.y;   // 0..7
#pragma unroll
  for (int i = ty; i < 32; i += 8)
    tile[i][tx] = src[(long long)(r0 + i) * sld + c0 + tx];
  __syncthreads();
#pragma unroll
  for (int i = ty; i < 32; i += 8)
    dst[(long long)(c0 + i) * dld + r0 + tx] = f2bf(tile[tx][i]);
}

// ---------------- bf16 [R][CC] (strided, batched) -> bf16 [CC][R] ----------------
__global__ __launch_bounds__(256)
void transpose_bf16(const u16* __restrict__ src, int sld, long long sbs,
                    u16* __restrict__ dst, int dld, long long dbs)
{
  src += (long long)blockIdx.z * sbs;
  dst += (long long)blockIdx.z * dbs;
  __shared__ u16 tile[32][33];
  const int c0 = blockIdx.x * 32;
  const int r0 = blockIdx.y * 32;
  const int tx = threadIdx.x;
  const int ty = threadIdx.y;
#pragma unroll
  for (int i = ty; i < 32; i += 8)
    tile[i][tx] = src[(long long)(r0 + i) * sld + c0 + tx];
  __syncthreads();
#pragma unroll
  for (int i = ty; i < 32; i += 8)
    dst[(long long)(c0 + i) * dld + r0 + tx] = tile[tx][i];
}

// C[M][N] = A[M][K] * Bt[N][K]^T  (NT GEMM), bf16 in, fp32 accum, OT out.
// 256x256 tile, 8 waves (2M x 4N), 128x64 output per wave, BK=32 double-buffered.
// Phase-split schedule (T2+T3+T4+T5): per K-tile, 2 phases of
// {ds_read -> barrier -> setprio + 16 MFMA -> barrier}; next tile's 4
// global_load_lds issued at top of phase 0 (front-loaded), single counted
// wait = vmcnt(0) at end of phase 1 (~2 phases after issue -> no drain stall).
// LDS XOR-swizzle (slot ^= row&3 on 16B slots) applied on BOTH sides per
// rule 21: linear LDS dest + inverse-permuted per-lane global src + swizzled
// ds_read. Verified: every frag read = 8 words/bank = conflict-free minimum.
// mode 0: plain; mode 1: causal skip (tile fully above diagonal -> return);
// mode 2: trim K to (bx+1)*BM (P@V with causal-zeroed probs);
// mode 3: plain, swapped block decode (bx=blockIdx.y) for A-tile L2 reuse.
// K (or trimmed kEnd) must be a multiple of BK.
template <typename OT>
__global__ __launch_bounds__(512, 2)
void gemm_nt(const u16* __restrict__ A, int lda, long long sA,
             const u16* __restrict__ Bt, int ldb, long long sB,
             OT* __restrict__ Cp, int ldc, long long sC,
             int K, const float* __restrict__ bias, float scale, int mode)
{
  int bx = blockIdx.x, by = blockIdx.y;
  const int bz = blockIdx.z;
  if (mode == 3) { bx = blockIdx.y; by = blockIdx.x; }
  if (mode == 1 && by > bx) return;
  A  += (long long)bz * sA;
  Bt += (long long)bz * sB;
  Cp += (long long)bz * sC;
  int kEnd = K;
  if (mode == 2) { int ke = (bx + 1) * BM; kEnd = ke < K ? ke : K; }

  // 2 x (256x32) for A and B = 64 KiB total (static LDS limit)
  __shared__ __align__(16) u16 As[2][BM * BK];
  __shared__ __align__(16) u16 Bs[2][BM * BK];

  const int tid  = threadIdx.x;
  const int wave = tid >> 6;      // 0..7
  const int lane = tid & 63;
  const int l16  = lane & 15;
  const int quad = lane >> 4;     // 0..3
  const int wm = wave >> 2;       // 0..1 -> rows wm*128..+127
  const int wn = wave & 3;        // 0..3 -> cols wn*64..+63

  // ds_read bases (element offsets), slot swizzled: slot = quad ^ (row&3).
  // row&3 == l16&3 for all frag rows (frag base is a multiple of 16).
  const int swz   = (quad ^ (l16 & 3)) << 3;
  const int abase = (wm * 128 + l16) * BK + swz;
  const int bbase = (wn * 64  + l16) * BK + swz;

  // staging: chunk = 1 KiB = 16 rows x 32 cols; lane l writes LDS linear
  // (chunk*512 + l*8) elems = row 16c+(l>>2), slot l&3. Source slot is the
  // involution-inverse: (l&3) ^ ((l>>2)&3). Wave w stages chunks {2w,2w+1}.
  const int ca   = wave * 2;
  const int srow = lane >> 2;                       // 0..15
  const int sxor = ((lane & 3) ^ (srow & 3)) * 8;   // source col (elems)
  const u16* Ag = A  + (long long)(bx * BM + ca * 16 + srow) * lda + sxor;
  const u16* Bg = Bt + (long long)(by * BN + ca * 16 + srow) * ldb + sxor;

#define STAGE(b, koff)                                                 \
  do {                                                                 \
    async_ld16(Ag + (koff),            &As[b][ca * 512]);              \
    async_ld16(Ag + (koff) + 16 * lda, &As[b][ca * 512 + 512]);        \
    async_ld16(Bg + (koff),            &Bs[b][ca * 512]);              \
    async_ld16(Bg + (koff) + 16 * ldb, &Bs[b][ca * 512 + 512]);        \
  } while (0)

  f32x4 zero4;
  zero4.x = zero4.y = zero4.z = zero4.w = 0.0f;
  f32x4 acc[8][4];
#pragma unroll
  for (int i = 0; i < 8; ++i)
#pragma unroll
    for (int j = 0; j < 4; ++j) acc[i][j] = zero4;

  const int nt = kEnd / BK;

  // prologue: tile 0 into buf 0
  STAGE(0, 0);
  asm volatile("s_waitcnt vmcnt(0)" ::: "memory");
  __builtin_amdgcn_s_barrier();
  asm volatile("" ::: "memory");

  int cur = 0;
  for (int t = 0; t < nt; ++t) {
    // ---- phase 0: issue next tile's loads early, compute m-frags 0-3 ----
    if (t + 1 < nt) STAGE(cur ^ 1, (t + 1) * BK);
    bf16x8 bv[4], av[4];
#pragma unroll
    for (int j = 0; j < 4; ++j) bv[j] = ldfrag(&Bs[cur][bbase + j * 512]);
#pragma unroll
    for (int i = 0; i < 4; ++i) av[i] = ldfrag(&As[cur][abase + i * 512]);
    asm volatile("" ::: "memory");
    __builtin_amdgcn_s_barrier();
    __builtin_amdgcn_s_setprio(1);
#pragma unroll
    for (int i = 0; i < 4; ++i)
#pragma unroll
      for (int j = 0; j < 4; ++j)
        acc[i][j] = __builtin_amdgcn_mfma_f32_16x16x32_bf16(av[i], bv[j], acc[i][j], 0, 0, 0);
    __builtin_amdgcn_s_setprio(0);
    asm volatile("" ::: "memory");
    __builtin_amdgcn_s_barrier();

    // ---- phase 1: m-frags 4-7 (bv reused from registers) ----
#pragma unroll
    for (int i = 0; i < 4; ++i) av[i] = ldfrag(&As[cur][abase + (i + 4) * 512]);
    asm volatile("" ::: "memory");
    __builtin_amdgcn_s_barrier();
    __builtin_amdgcn_s_setprio(1);
#pragma unroll
    for (int i = 0; i < 4; ++i)
#pragma unroll
      for (int j = 0; j < 4; ++j)
        acc[i + 4][j] = __builtin_amdgcn_mfma_f32_16x16x32_bf16(av[i], bv[j], acc[i + 4][j], 0, 0, 0);
    __builtin_amdgcn_s_setprio(0);
    // loads for tile t+1 were issued ~2 phases ago -> this wait is ~free
    asm volatile("s_waitcnt vmcnt(0)" ::: "memory");
    __builtin_amdgcn_s_barrier();
    asm volatile("" ::: "memory");
    cur ^= 1;
  }
#undef STAGE

  // epilogue: C/D layout col = lane&15, row = quad*4 + reg (verified m89/m91)
  const long long row0 = (long long)bx * BM + wm * 128 + quad * 4;
  const int col0 = by * BN + wn * 64 + l16;
#pragma unroll
  for (int j = 0; j < 4; ++j) {
    const int col = col0 + j * 16;
    const float bval = bias ? bias[col] : 0.0f;
#pragma unroll
    for (int i = 0; i < 8; ++i) {
#pragma unroll
      for (int r = 0; r < 4; ++r) {
        const long long row = row0 + i * 16 + r;
        cstore(&Cp[row * ldc + col], acc[i][j][r] * scale + bval);
      }
    }
  }
}

// causal softmax over one row of [T] bf16 scores, in place.
// Vectorized: thread t owns elements [8t, 8t+8). Writes only [0, Lw) where
// Lw = ceil(L/256)*256 — exactly the range the K-trimmed (BM=256) PV GEMM reads.
// requires T == 2048 (8 elems/thread * 256 threads)
__global__ __launch_bounds__(256)
void softmax_causal(u16* __restrict__ sc, int T)
{
  const int row = blockIdx.x;       // z*T + t
  const int t = row & (T - 1);
  u16* p = sc + (long long)row * T;
  const int L  = t + 1;
  const int Lw = ((t >> 8) + 1) << 8;   // 256-aligned for BM=256 PV trim
  const int tid = threadIdx.x;
  const int lane = tid & 63;
  const int wave = tid >> 6;
  const int base = tid * 8;

  const u16x8 in = *(const u16x8*)(p + base);
  float v[8];
  float m = -1e30f;
#pragma unroll
  for (int e = 0; e < 8; ++e) {
    const float f = bf2f(in[e]);
    v[e] = (base + e < L) ? f : -1e30f;
    m = fmaxf(m, v[e]);
  }
#pragma unroll
  for (int o = 32; o > 0; o >>= 1) m = fmaxf(m, __shfl_xor(m, o, 64));
  __shared__ float redm[4], reds[4];
  if (lane == 0) redm[wave] = m;
  __syncthreads();
  m = fmaxf(fmaxf(redm[0], redm[1]), fmaxf(redm[2], redm[3]));

  float s = 0.0f;
#pragma unroll
  for (int e = 0; e < 8; ++e) {
    const float ex = __expf(v[e] - m);       // v==-1e30 -> 0
    v[e] = (base + e < L) ? ex : 0.0f;
    s += v[e];
  }
#pragma unroll
  for (int o = 32; o > 0; o >>= 1) s += __shfl_xor(s, o, 64);
  if (lane == 0) reds[wave] = s;
  __syncthreads();
  s = reds[0] + reds[1] + reds[2] + reds[3];
  const float inv = 1.0f / s;

  if (base < Lw) {
    u16x8 o8;
#pragma unroll
    for (int e = 0; e < 8; ++e) o8[e] = f2bf(v[e] * inv);
    *(u16x8*)(p + base) = o8;
  }
}

extern "C" void kernel_launch(void* const* d_in, const int* in_sizes, int n_in,
                              void* d_out, int out_size, void* d_ws, size_t ws_size,
                              hipStream_t stream)
{
  (void)in_sizes; (void)n_in; (void)out_size; (void)ws_size;
  const int B = 8, T = 2048, C = 1024;
  const int M = B * T;        // 16384
  const int C3 = 3 * C;       // 3072

  // inputs AND output are FP32 (reference dtypes)
  const float* x     = (const float*)d_in[0];
  const float* Wkqv  = (const float*)d_in[1];
  const float* bkqv  = (const float*)d_in[2];
  const float* Wproj = (const float*)d_in[3];
  const float* bproj = (const float*)d_in[4];
  float* out = (float*)d_out;

  // Workspace: 232 MiB footprint (proven to fit). xb dead after GEMM1; ao aliases it.
  char* w = (char*)d_ws;
  u16* xb     = (u16*)w; w += (size_t)M * C * 2;        // 33.5 MB [M][C]  (aliased by ao)
  u16* WkqvT  = (u16*)w; w += (size_t)C3 * C * 2;       //  6.3 MB [3C][C]
  u16* WprojT = (u16*)w; w += (size_t)C * C * 2;        //  2.1 MB [C][C]
  u16* kqv    = (u16*)w; w += (size_t)M * C3 * 2;       // 100.7 MB [M][3C]
  u16* vT     = (u16*)w; w += (size_t)B * C * T * 2;    // 33.5 MB [B][C][T]
  u16* sc     = (u16*)w; w += (size_t)B * T * T * 2;    // 67.1 MB [B][T][T]
  u16* ao     = xb;                                     // alias: lifetimes disjoint

  dim3 tb(32, 8);

  // x -> bf16
  f32_to_bf16<<<(M * C) / 1024, 256, 0, stream>>>(x, xb);

  // weights -> bf16, NT layout
  transpose_f2b<<<dim3(C3 / 32, C / 32, 1), tb, 0, stream>>>(Wkqv, C3, WkqvT, C);
  transpose_f2b<<<dim3(C / 32, C / 32, 1), tb, 0, stream>>>(Wproj, C, WprojT, C);

  // kqv = x @ W_kqv + b_kqv  [M][3C]. mode 3: N fastest -> consecutive blocks
  // share the x row-tile (less HBM refetch).
  gemm_nt<u16><<<dim3(C3 / BN, M / BM, 1), 512, 0, stream>>>(
      xb, C, 0, WkqvT, C, 0, kqv, C3, 0, C, bkqv, 1.0f, 3);

  // v[T][C] (stride 3C, per batch) -> vT[C][T]
  transpose_bf16<<<dim3(C / 32, T / 32, B), tb, 0, stream>>>(
      kqv + 2 * C, C3, (long long)T * C3, vT, T, (long long)C * T);

  // scores = q @ k^T * (1/sqrt(T)), lower-triangular tiles only
  gemm_nt<u16><<<dim3(T / BM, T / BN, B), 512, 0, stream>>>(
      kqv + C, C3, (long long)T * C3, kqv, C3, (long long)T * C3,
      sc, T, (long long)T * T, C, nullptr, 0.022097086912079608f, 1);

  // causal softmax in place (writes zeros through the diagonal tile only)
  softmax_causal<<<B * T, 256, 0, stream>>>(sc, T);

  // ao = probs @ v  (NT against vT), K trimmed per tile row; ao aliases xb
  gemm_nt<u16><<<dim3(T / BM, C / BN, B), 512, 0, stream>>>(
      sc, T, (long long)T * T, vT, T, (long long)C * T,
      ao, C, (long long)T * C, T, nullptr, 1.0f, 2);

  // out = ao @ W_proj + b_proj   -- FP32 output
  gemm_nt<float><<<dim3(M / BM, C / BN, 1), 512, 0, stream>>>(
      ao, C, 0, WprojT, C, 0, out, C, 0, C, bproj, 1.0f, 0);
}

// Round 2
// 502.920 us; speedup vs baseline: 1.2031x; 1.2031x over previous
//
#include <hip/hip_runtime.h>

typedef unsigned short u16;
typedef __attribute__((ext_vector_type(8))) __bf16 bf16x8;
typedef __attribute__((ext_vector_type(8))) unsigned short u16x8;
typedef __attribute__((ext_vector_type(4))) unsigned short u16x4;
typedef __attribute__((ext_vector_type(4))) float f32x4;

#define BM 256
#define BN 256
#define BK 64   // K-step per LDS buffer; double-buffered (128 KiB total)

__device__ __forceinline__ float bf2f(u16 x) {
  union { unsigned int u; float f; } un;
  un.u = ((unsigned int)x) << 16;
  return un.f;
}

__device__ __forceinline__ u16 f2bf(float f) {
  union { float f; unsigned int u; } un;
  un.f = f;
  unsigned int r = un.u + 0x7fffu + ((un.u >> 16) & 1u);
  return (u16)(r >> 16);
}

__device__ __forceinline__ void cstore(u16* p, float v)   { *p = f2bf(v); }
__device__ __forceinline__ void cstore(float* p, float v) { *p = v; }

// async global->LDS, 16B per lane; lds dst is wave-uniform base (HW adds lane*16B)
__device__ __forceinline__ void async_ld16(const u16* g, u16* l) {
  __builtin_amdgcn_global_load_lds(
      (const __attribute__((address_space(1))) unsigned int*)g,
      (__attribute__((address_space(3))) unsigned int*)l, 16, 0, 0);
}

__device__ __forceinline__ bf16x8 ldfrag(const u16* p) {
  union { u16x8 u; bf16x8 b; } c;
  c.u = *(const u16x8*)p;
  return c.b;
}

// ---------------- fp32 -> bf16 elementwise (x), 4 elems/thread ----------------
__global__ __launch_bounds__(256)
void f32_to_bf16(const float* __restrict__ s, u16* __restrict__ d)
{
  const int i = blockIdx.x * 256 + threadIdx.x;
  const float4 v = ((const float4*)s)[i];
  u16x4 o;
  o.x = f2bf(v.x); o.y = f2bf(v.y); o.z = f2bf(v.z); o.w = f2bf(v.w);
  ((u16x4*)d)[i] = o;
}

// ---------------- fp32 [R][CC] -> bf16 transposed [CC][R] ----------------
__global__ __launch_bounds__(256)
void transpose_f2b(const float* __restrict__ src, int sld,
                   u16* __restrict__ dst, int dld)
{
  __shared__ float tile[32][33];
  const int c0 = blockIdx.x * 32;
  const int r0 = blockIdx.y * 32;
  const int tx = threadIdx.x;   // 0..31
  const int ty = threadIdx.y;   // 0..7
#pragma unroll
  for (int i = ty; i < 32; i += 8)
    tile[i][tx] = src[(long long)(r0 + i) * sld + c0 + tx];
  __syncthreads();
#pragma unroll
  for (int i = ty; i < 32; i += 8)
    dst[(long long)(c0 + i) * dld + r0 + tx] = f2bf(tile[tx][i]);
}

// ---------------- bf16 [R][CC] (strided, batched) -> bf16 [CC][R] ----------------
__global__ __launch_bounds__(256)
void transpose_bf16(const u16* __restrict__ src, int sld, long long sbs,
                    u16* __restrict__ dst, int dld, long long dbs)
{
  src += (long long)blockIdx.z * sbs;
  dst += (long long)blockIdx.z * dbs;
  __shared__ u16 tile[32][33];
  const int c0 = blockIdx.x * 32;
  const int r0 = blockIdx.y * 32;
  const int tx = threadIdx.x;
  const int ty = threadIdx.y;
#pragma unroll
  for (int i = ty; i < 32; i += 8)
    tile[i][tx] = src[(long long)(r0 + i) * sld + c0 + tx];
  __syncthreads();
#pragma unroll
  for (int i = ty; i < 32; i += 8)
    dst[(long long)(c0 + i) * dld + r0 + tx] = tile[tx][i];
}

// C[M][N] = A[M][K] * Bt[N][K]^T  (NT GEMM), bf16 in, fp32 accum, OT out.
// m201-style 256x256 template: BK=64 double-buffered (128 KiB LDS), 8 waves
// (2M x 4N, 128x64 out/wave), 4 phases per K-tile of {8-or-4 ds_read | 2
// global_load_lds prefetch | barrier | setprio+16 MFMA | barrier}, COUNTED
// vmcnt (never 0 in steady state): vmcnt(4) end-P2 (A-2nd-half of tile j,
// issued 3 phases earlier), vmcnt(2) end-P4 (B + A-1st of tile j+1).
// LDS bank swizzle: row = 128B -> bank = f(16B-slot only); slot ^= row&7
// spreads each b128 frag read uniformly: 8 lanes/slot = 8 words/bank (floor).
// Both-sides rule: linear LDS dest, inverse-permuted global src
// (col = ((lane&7)^(lane>>3))*8, chunk-independent), XOR'd ds_read addr.
// mode 0: plain; mode 1: causal skip; mode 2: K trimmed to (bx+1)*BM;
// mode 3: plain, swapped block decode. kEnd must be a multiple of 64.
template <typename OT>
__global__ __launch_bounds__(512, 2)
void gemm_nt(const u16* __restrict__ A, int lda, long long sA,
             const u16* __restrict__ Bt, int ldb, long long sB,
             OT* __restrict__ Cp, int ldc, long long sC,
             int K, const float* __restrict__ bias, float scale, int mode)
{
  int bx = blockIdx.x, by = blockIdx.y;
  const int bz = blockIdx.z;
  if (mode == 3) { bx = blockIdx.y; by = blockIdx.x; }
  if (mode == 1 && by > bx) return;
  A  += (long long)bz * sA;
  Bt += (long long)bz * sB;
  Cp += (long long)bz * sC;
  int kEnd = K;
  if (mode == 2) { int ke = (bx + 1) * BM; kEnd = ke < K ? ke : K; }

  // 2 x (256x64) for A and B = 128 KiB (gfx950 LDS/CU = 160 KiB; 1 block/CU)
  __shared__ __align__(16) u16 As[2][BM * BK];
  __shared__ __align__(16) u16 Bs[2][BM * BK];

  const int tid  = threadIdx.x;
  const int wave = tid >> 6;      // 0..7
  const int lane = tid & 63;
  const int l16  = lane & 15;
  const int quad = lane >> 4;     // 0..3
  const int wm = wave >> 2;       // 0..1 -> rows wm*128..+127
  const int wn = wave & 3;        // 0..3 -> cols wn*64..+63

  // ds_read slot (16B units) = (kk*4+quad) ^ (row&7); row&7 == l16&7 (frag
  // bases are multiples of 16). Element offsets within a 64-elem row:
  const int sk0 = ((quad    ) ^ (l16 & 7)) * 8;   // kk = 0
  const int sk1 = ((quad + 4) ^ (l16 & 7)) * 8;   // kk = 1
  const int arow = wm * 128 + l16;                // + i*16 per M-frag
  const int brow = wn * 64  + l16;                // + n*16 per N-frag

  // staging: chunk = 1 KiB = 8 rows x 64 cols. global_load_lds writes LDS
  // linearly: lane l -> row chunk*8 + (l>>3), slot l&7. Source column is the
  // swizzle-inverse: ((l&7) ^ (l>>3)) * 8 elems (chunk-independent).
  const int srow8 = lane >> 3;                    // 0..7
  const int sx    = ((lane & 7) ^ srow8) * 8;     // elems

  // chunk ownership: wave w stages B chunks {4w..4w+3};
  // A first-half rows (M-frags 0-3: rows 0-63 & 128-191 = chunks 0-7,16-23):
  // waves 0-3 -> {2w,2w+1}, waves 4-7 -> {16+2(w-4), +1}; second half = +8.
  const int f0 = (wave < 4) ? (2 * wave) : (16 + 2 * (wave - 4));
  const int aCh[4] = { f0, f0 + 1, f0 + 8, f0 + 9 };

  const u16* Bgp[4];
#pragma unroll
  for (int p = 0; p < 4; ++p)
    Bgp[p] = Bt + (long long)(by * BN + (4 * wave + p) * 8 + srow8) * ldb + sx;
  const u16* Agp[4];
#pragma unroll
  for (int q = 0; q < 4; ++q)
    Agp[q] = A + (long long)(bx * BM + aCh[q] * 8 + srow8) * lda + sx;

  f32x4 zero4;
  zero4.x = zero4.y = zero4.z = zero4.w = 0.0f;
  f32x4 acc[8][4];
#pragma unroll
  for (int i = 0; i < 8; ++i)
#pragma unroll
    for (int j = 0; j < 4; ++j) acc[i][j] = zero4;

  const int nt = kEnd / BK;

  // prologue: tile 0 -> buf 0; issue order B0-3, Af0, Af1, As0, As1 so that
  // vmcnt(2) completes B + A-first (P1/P2 inputs), leaving A-second in flight.
#pragma unroll
  for (int p = 0; p < 4; ++p) async_ld16(Bgp[p], &Bs[0][(4 * wave + p) * 512]);
#pragma unroll
  for (int q = 0; q < 4; ++q) async_ld16(Agp[q], &As[0][aCh[q] * 512]);
  asm volatile("s_waitcnt vmcnt(2)" ::: "memory");
  __builtin_amdgcn_s_barrier();

  for (int j = 0; j < nt; ++j) {
    const int cur = j & 1;
    const int nxt = cur ^ 1;
    const bool pf = (j + 1 < nt);
    const int ko = (j + 1) * BK;   // next tile's K offset (elems)

    bf16x8 bv0[4], bv1[4], av[4];

    // ---- P1: M-frags 0-3 x N-frags 0-3, kk=0 ----
#pragma unroll
    for (int n = 0; n < 4; ++n) bv0[n] = ldfrag(&Bs[cur][(brow + n * 16) * BK + sk0]);
#pragma unroll
    for (int i = 0; i < 4; ++i) av[i]  = ldfrag(&As[cur][(arow + i * 16) * BK + sk0]);
    if (pf) {
      async_ld16(Bgp[0] + ko, &Bs[nxt][(4 * wave + 0) * 512]);
      async_ld16(Bgp[1] + ko, &Bs[nxt][(4 * wave + 1) * 512]);
    }
    asm volatile("" ::: "memory");
    __builtin_amdgcn_s_barrier();
    __builtin_amdgcn_s_setprio(1);
#pragma unroll
    for (int i = 0; i < 4; ++i)
#pragma unroll
      for (int n = 0; n < 4; ++n)
        acc[i][n] = __builtin_amdgcn_mfma_f32_16x16x32_bf16(av[i], bv0[n], acc[i][n], 0, 0, 0);
    __builtin_amdgcn_s_setprio(0);
    asm volatile("" ::: "memory");
    __builtin_amdgcn_s_barrier();

    // ---- P2: M-frags 0-3 x N-frags 0-3, kk=1 ----
#pragma unroll
    for (int n = 0; n < 4; ++n) bv1[n] = ldfrag(&Bs[cur][(brow + n * 16) * BK + sk1]);
#pragma unroll
    for (int i = 0; i < 4; ++i) av[i]  = ldfrag(&As[cur][(arow + i * 16) * BK + sk1]);
    if (pf) {
      async_ld16(Bgp[2] + ko, &Bs[nxt][(4 * wave + 2) * 512]);
      async_ld16(Bgp[3] + ko, &Bs[nxt][(4 * wave + 3) * 512]);
    }
    asm volatile("" ::: "memory");
    __builtin_amdgcn_s_barrier();
    __builtin_amdgcn_s_setprio(1);
#pragma unroll
    for (int i = 0; i < 4; ++i)
#pragma unroll
      for (int n = 0; n < 4; ++n)
        acc[i][n] = __builtin_amdgcn_mfma_f32_16x16x32_bf16(av[i], bv1[n], acc[i][n], 0, 0, 0);
    __builtin_amdgcn_s_setprio(0);
    // A-second-half of tile j (issued 3 phases ago) must land before P3 reads;
    // the 4 newest (B of tile j+1) stay in flight.
    if (pf) asm volatile("s_waitcnt vmcnt(4)" ::: "memory");
    else    asm volatile("s_waitcnt vmcnt(0)" ::: "memory");
    __builtin_amdgcn_s_barrier();

    // ---- P3: M-frags 4-7 x N-frags 0-3, kk=0 (bv0 reused from registers) ----
#pragma unroll
    for (int i = 0; i < 4; ++i) av[i] = ldfrag(&As[cur][(arow + (i + 4) * 16) * BK + sk0]);
    if (pf) {
      async_ld16(Agp[0] + ko, &As[nxt][aCh[0] * 512]);
      async_ld16(Agp[1] + ko, &As[nxt][aCh[1] * 512]);
    }
    asm volatile("" ::: "memory");
    __builtin_amdgcn_s_barrier();
    __builtin_amdgcn_s_setprio(1);
#pragma unroll
    for (int i = 0; i < 4; ++i)
#pragma unroll
      for (int n = 0; n < 4; ++n)
        acc[i + 4][n] = __builtin_amdgcn_mfma_f32_16x16x32_bf16(av[i], bv0[n], acc[i + 4][n], 0, 0, 0);
    __builtin_amdgcn_s_setprio(0);
    asm volatile("" ::: "memory");
    __builtin_amdgcn_s_barrier();

    // ---- P4: M-frags 4-7 x N-frags 0-3, kk=1 (bv1 reused) ----
#pragma unroll
    for (int i = 0; i < 4; ++i) av[i] = ldfrag(&As[cur][(arow + (i + 4) * 16) * BK + sk1]);
    if (pf) {
      async_ld16(Agp[2] + ko, &As[nxt][aCh[2] * 512]);
      async_ld16(Agp[3] + ko, &As[nxt][aCh[3] * 512]);
    }
    asm volatile("" ::: "memory");
    __builtin_amdgcn_s_barrier();
    __builtin_amdgcn_s_setprio(1);
#pragma unroll
    for (int i = 0; i < 4; ++i)
#pragma unroll
      for (int n = 0; n < 4; ++n)
        acc[i + 4][n] = __builtin_amdgcn_mfma_f32_16x16x32_bf16(av[i], bv1[n], acc[i + 4][n], 0, 0, 0);
    __builtin_amdgcn_s_setprio(0);
    // B + A-first of tile j+1 must land before next P1; A-second (the 2
    // newest, issued this phase) stays in flight.
    if (pf) asm volatile("s_waitcnt vmcnt(2)" ::: "memory");
    __builtin_amdgcn_s_barrier();
  }

  // epilogue: C/D layout col = lane&15, row = quad*4 + reg (verified m89/m91)
  const long long row0 = (long long)bx * BM + wm * 128 + quad * 4;
  const int col0 = by * BN + wn * 64 + l16;
#pragma unroll
  for (int j = 0; j < 4; ++j) {
    const int col = col0 + j * 16;
    const float bval = bias ? bias[col] : 0.0f;
#pragma unroll
    for (int i = 0; i < 8; ++i) {
#pragma unroll
      for (int r = 0; r < 4; ++r) {
        const long long row = row0 + i * 16 + r;
        cstore(&Cp[row * ldc + col], acc[i][j][r] * scale + bval);
      }
    }
  }
}

// causal softmax over one row of [T] bf16 scores, in place.
// Vectorized: thread t owns elements [8t, 8t+8). Writes only [0, Lw) where
// Lw = ceil(L/256)*256 — exactly the range the K-trimmed (BM=256) PV GEMM reads.
// requires T == 2048 (8 elems/thread * 256 threads)
__global__ __launch_bounds__(256)
void softmax_causal(u16* __restrict__ sc, int T)
{
  const int row = blockIdx.x;       // z*T + t
  const int t = row & (T - 1);
  u16* p = sc + (long long)row * T;
  const int L  = t + 1;
  const int Lw = ((t >> 8) + 1) << 8;   // 256-aligned for BM=256 PV trim
  const int tid = threadIdx.x;
  const int lane = tid & 63;
  const int wave = tid >> 6;
  const int base = tid * 8;

  const u16x8 in = *(const u16x8*)(p + base);
  float v[8];
  float m = -1e30f;
#pragma unroll
  for (int e = 0; e < 8; ++e) {
    const float f = bf2f(in[e]);
    v[e] = (base + e < L) ? f : -1e30f;
    m = fmaxf(m, v[e]);
  }
#pragma unroll
  for (int o = 32; o > 0; o >>= 1) m = fmaxf(m, __shfl_xor(m, o, 64));
  __shared__ float redm[4], reds[4];
  if (lane == 0) redm[wave] = m;
  __syncthreads();
  m = fmaxf(fmaxf(redm[0], redm[1]), fmaxf(redm[2], redm[3]));

  float s = 0.0f;
#pragma unroll
  for (int e = 0; e < 8; ++e) {
    const float ex = __expf(v[e] - m);       // v==-1e30 -> 0
    v[e] = (base + e < L) ? ex : 0.0f;
    s += v[e];
  }
#pragma unroll
  for (int o = 32; o > 0; o >>= 1) s += __shfl_xor(s, o, 64);
  if (lane == 0) reds[wave] = s;
  __syncthreads();
  s = reds[0] + reds[1] + reds[2] + reds[3];
  const float inv = 1.0f / s;

  if (base < Lw) {
    u16x8 o8;
#pragma unroll
    for (int e = 0; e < 8; ++e) o8[e] = f2bf(v[e] * inv);
    *(u16x8*)(p + base) = o8;
  }
}

extern "C" void kernel_launch(void* const* d_in, const int* in_sizes, int n_in,
                              void* d_out, int out_size, void* d_ws, size_t ws_size,
                              hipStream_t stream)
{
  (void)in_sizes; (void)n_in; (void)out_size; (void)ws_size;
  const int B = 8, T = 2048, C = 1024;
  const int M = B * T;        // 16384
  const int C3 = 3 * C;       // 3072

  // inputs AND output are FP32 (reference dtypes)
  const float* x     = (const float*)d_in[0];
  const float* Wkqv  = (const float*)d_in[1];
  const float* bkqv  = (const float*)d_in[2];
  const float* Wproj = (const float*)d_in[3];
  const float* bproj = (const float*)d_in[4];
  float* out = (float*)d_out;

  // Workspace: 232 MiB footprint (proven to fit). xb dead after GEMM1; ao aliases it.
  char* w = (char*)d_ws;
  u16* xb     = (u16*)w; w += (size_t)M * C * 2;        // 33.5 MB [M][C]  (aliased by ao)
  u16* WkqvT  = (u16*)w; w += (size_t)C3 * C * 2;       //  6.3 MB [3C][C]
  u16* WprojT = (u16*)w; w += (size_t)C * C * 2;        //  2.1 MB [C][C]
  u16* kqv    = (u16*)w; w += (size_t)M * C3 * 2;       // 100.7 MB [M][3C]
  u16* vT     = (u16*)w; w += (size_t)B * C * T * 2;    // 33.5 MB [B][C][T]
  u16* sc     = (u16*)w; w += (size_t)B * T * T * 2;    // 67.1 MB [B][T][T]
  u16* ao     = xb;                                     // alias: lifetimes disjoint

  dim3 tb(32, 8);

  // x -> bf16
  f32_to_bf16<<<(M * C) / 1024, 256, 0, stream>>>(x, xb);

  // weights -> bf16, NT layout
  transpose_f2b<<<dim3(C3 / 32, C / 32, 1), tb, 0, stream>>>(Wkqv, C3, WkqvT, C);
  transpose_f2b<<<dim3(C / 32, C / 32, 1), tb, 0, stream>>>(Wproj, C, WprojT, C);

  // kqv = x @ W_kqv + b_kqv  [M][3C]. mode 3: N fastest -> consecutive blocks
  // share the x row-tile (less HBM refetch).
  gemm_nt<u16><<<dim3(C3 / BN, M / BM, 1), 512, 0, stream>>>(
      xb, C, 0, WkqvT, C, 0, kqv, C3, 0, C, bkqv, 1.0f, 3);

  // v[T][C] (stride 3C, per batch) -> vT[C][T]
  transpose_bf16<<<dim3(C / 32, T / 32, B), tb, 0, stream>>>(
      kqv + 2 * C, C3, (long long)T * C3, vT, T, (long long)C * T);

  // scores = q @ k^T * (1/sqrt(T)), lower-triangular tiles only
  gemm_nt<u16><<<dim3(T / BM, T / BN, B), 512, 0, stream>>>(
      kqv + C, C3, (long long)T * C3, kqv, C3, (long long)T * C3,
      sc, T, (long long)T * T, C, nullptr, 0.022097086912079608f, 1);

  // causal softmax in place (writes zeros through the diagonal tile only)
  softmax_causal<<<B * T, 256, 0, stream>>>(sc, T);

  // ao = probs @ v  (NT against vT), K trimmed per tile row; ao aliases xb
  gemm_nt<u16><<<dim3(T / BM, C / BN, B), 512, 0, stream>>>(
      sc, T, (long long)T * T, vT, T, (long long)C * T,
      ao, C, (long long)T * C, T, nullptr, 1.0f, 2);

  // out = ao @ W_proj + b_proj   -- FP32 output
  gemm_nt<float><<<dim3(M / BM, C / BN, 1), 512, 0, stream>>>(
      ao, C, 0, WprojT, C, 0, out, C, 0, C, bproj, 1.0f, 0);
}

// Round 3
// 468.282 us; speedup vs baseline: 1.2921x; 1.0740x over previous
//
#include <hip/hip_runtime.h>

typedef unsigned short u16;
typedef __attribute__((ext_vector_type(8))) __bf16 bf16x8;
typedef __attribute__((ext_vector_type(8))) unsigned short u16x8;
typedef __attribute__((ext_vector_type(4))) unsigned short u16x4;
typedef __attribute__((ext_vector_type(4))) float f32x4;

#define BM 256
#define BN 256
#define BK 64   // K-step per LDS buffer; double-buffered (128 KiB total)

__device__ __forceinline__ float bf2f(u16 x) {
  union { unsigned int u; float f; } un;
  un.u = ((unsigned int)x) << 16;
  return un.f;
}

__device__ __forceinline__ u16 f2bf(float f) {
  union { float f; unsigned int u; } un;
  un.f = f;
  unsigned int r = un.u + 0x7fffu + ((un.u >> 16) & 1u);
  return (u16)(r >> 16);
}

__device__ __forceinline__ void cstore(u16* p, float v)   { *p = f2bf(v); }
__device__ __forceinline__ void cstore(float* p, float v) { *p = v; }

// async global->LDS, 16B per lane; lds dst is wave-uniform base (HW adds lane*16B)
__device__ __forceinline__ void async_ld16(const u16* g, u16* l) {
  __builtin_amdgcn_global_load_lds(
      (const __attribute__((address_space(1))) unsigned int*)g,
      (__attribute__((address_space(3))) unsigned int*)l, 16, 0, 0);
}

__device__ __forceinline__ bf16x8 ldfrag(const u16* p) {
  union { u16x8 u; bf16x8 b; } c;
  c.u = *(const u16x8*)p;
  return c.b;
}

// ---------------- fp32 -> bf16 elementwise (x), 4 elems/thread ----------------
__global__ __launch_bounds__(256)
void f32_to_bf16(const float* __restrict__ s, u16* __restrict__ d)
{
  const int i = blockIdx.x * 256 + threadIdx.x;
  const float4 v = ((const float4*)s)[i];
  u16x4 o;
  o.x = f2bf(v.x); o.y = f2bf(v.y); o.z = f2bf(v.z); o.w = f2bf(v.w);
  ((u16x4*)d)[i] = o;
}

// ---------------- fp32 [R][CC] -> bf16 transposed [CC][R] ----------------
__global__ __launch_bounds__(256)
void transpose_f2b(const float* __restrict__ src, int sld,
                   u16* __restrict__ dst, int dld)
{
  __shared__ float tile[32][33];
  const int c0 = blockIdx.x * 32;
  const int r0 = blockIdx.y * 32;
  const int tx = threadIdx.x;   // 0..31
  const int ty = threadIdx.y;   // 0..7
#pragma unroll
  for (int i = ty; i < 32; i += 8)
    tile[i][tx] = src[(long long)(r0 + i) * sld + c0 + tx];
  __syncthreads();
#pragma unroll
  for (int i = ty; i < 32; i += 8)
    dst[(long long)(c0 + i) * dld + r0 + tx] = f2bf(tile[tx][i]);
}

// C[M][N] = A[M][K] * Bt[N][K]^T  (NT GEMM), bf16 in, fp32 accum, OT out.
// 256x256 tile, BK=64 double-buffered (128 KiB LDS), 8 waves (2M x 4N,
// 128x64 out/wave), 4 phases/K-tile, 16 MFMA each. Register-pipelined frag
// reads (derived-waits style): P1 slot issues BOTH P1 and P2 fragments
// (R1+R2, 16 ds_read_b128); P3 slot issues P3+P4 (R3+R4, 8). The compiler's
// per-register lgkm waits make P2/P4's waits free — R2/R4 are served by the
// LDS FIFO *under* the P1/P3 MFMA bursts. Staging order and counted vmcnt
// are byte-identical to the verified round-2 ledger:
//   stage B01@P1, B23@P2, A01@P3, A23@P4 (for tile j+1)
//   end-P2: vmcnt(4)  -> A23 of tile j landed (needed by P3-slot reads)
//   end-P4: vmcnt(2)  -> B01,B23,A01 of tile j+1 landed (needed by next P1)
// LDS bank swizzle (slot ^= row&7 on 16B slots), both-sides rule: linear
// global_load_lds dest + inverse-permuted global src + XOR'd ds_read.
// mode 0: plain; mode 1: causal skip; mode 2: K trimmed to (bx+1)*BM;
// mode 3: plain, swapped block decode. kEnd must be a multiple of 64.
// vdst != nullptr: blocks with N-base >= 2048 write u16 output TRANSPOSED
// into vdst[b][col-2048][row%2048] (fused V-transpose for the kqv GEMM)
// instead of Cp.
template <typename OT>
__global__ __launch_bounds__(512, 2)
void gemm_nt(const u16* __restrict__ A, int lda, long long sA,
             const u16* __restrict__ Bt, int ldb, long long sB,
             OT* __restrict__ Cp, int ldc, long long sC,
             int K, const float* __restrict__ bias, float scale, int mode,
             u16* __restrict__ vdst)
{
  int bx = blockIdx.x, by = blockIdx.y;
  const int bz = blockIdx.z;
  if (mode == 3) { bx = blockIdx.y; by = blockIdx.x; }
  if (mode == 1 && by > bx) return;
  A  += (long long)bz * sA;
  Bt += (long long)bz * sB;
  Cp += (long long)bz * sC;
  int kEnd = K;
  if (mode == 2) { int ke = (bx + 1) * BM; kEnd = ke < K ? ke : K; }

  __shared__ __align__(16) u16 As[2][BM * BK];
  __shared__ __align__(16) u16 Bs[2][BM * BK];

  const int tid  = threadIdx.x;
  const int wave = tid >> 6;      // 0..7
  const int lane = tid & 63;
  const int l16  = lane & 15;
  const int quad = lane >> 4;     // 0..3
  const int wm = wave >> 2;       // 0..1 -> rows wm*128..+127
  const int wn = wave & 3;        // 0..3 -> cols wn*64..+63

  // ds_read slot (16B units) = (kk*4+quad) ^ (row&7); row&7 == l16&7.
  const int sk0 = ((quad    ) ^ (l16 & 7)) * 8;   // kk = 0
  const int sk1 = ((quad + 4) ^ (l16 & 7)) * 8;   // kk = 1
  const int arow = wm * 128 + l16;
  const int brow = wn * 64  + l16;

  // staging: chunk = 1 KiB = 8 rows x 64 cols; lane l -> row chunk*8+(l>>3),
  // slot l&7; source col = swizzle-inverse ((l&7)^(l>>3))*8 elems.
  const int srow8 = lane >> 3;
  const int sx    = ((lane & 7) ^ srow8) * 8;

  // wave w stages B chunks {4w..4w+3}; A chunks: first-half {f0,f0+1},
  // second-half {f0+8,f0+9}.
  const int f0 = (wave < 4) ? (2 * wave) : (16 + 2 * (wave - 4));
  const int aCh[4] = { f0, f0 + 1, f0 + 8, f0 + 9 };

  const u16* Bgp[4];
#pragma unroll
  for (int p = 0; p < 4; ++p)
    Bgp[p] = Bt + (long long)(by * BN + (4 * wave + p) * 8 + srow8) * ldb + sx;
  const u16* Agp[4];
#pragma unroll
  for (int q = 0; q < 4; ++q)
    Agp[q] = A + (long long)(bx * BM + aCh[q] * 8 + srow8) * lda + sx;

  f32x4 zero4;
  zero4.x = zero4.y = zero4.z = zero4.w = 0.0f;
  f32x4 acc[8][4];
#pragma unroll
  for (int i = 0; i < 8; ++i)
#pragma unroll
    for (int j = 0; j < 4; ++j) acc[i][j] = zero4;

  const int nt = kEnd / BK;

  // prologue: tile 0 -> buf 0; order B0-3, A0-3; vmcnt(2) leaves A-second
  // (aCh[2],aCh[3]) in flight -- landed by end-P2's vmcnt(4).
#pragma unroll
  for (int p = 0; p < 4; ++p) async_ld16(Bgp[p], &Bs[0][(4 * wave + p) * 512]);
#pragma unroll
  for (int q = 0; q < 4; ++q) async_ld16(Agp[q], &As[0][aCh[q] * 512]);
  asm volatile("s_waitcnt vmcnt(2)" ::: "memory");
  __builtin_amdgcn_s_barrier();

  for (int j = 0; j < nt; ++j) {
    const int cur = j & 1;
    const int nxt = cur ^ 1;
    const bool pf = (j + 1 < nt);
    const int ko = (j + 1) * BK;

    bf16x8 bv0[4], bv1[4], av0[4], av1[4];

    // ---- P1 slot: issue R1 (P1 frags) AND R2 (P2 frags) ----
#pragma unroll
    for (int n = 0; n < 4; ++n) bv0[n] = ldfrag(&Bs[cur][(brow + n * 16) * BK + sk0]);
#pragma unroll
    for (int i = 0; i < 4; ++i) av0[i] = ldfrag(&As[cur][(arow + i * 16) * BK + sk0]);
#pragma unroll
    for (int n = 0; n < 4; ++n) bv1[n] = ldfrag(&Bs[cur][(brow + n * 16) * BK + sk1]);
#pragma unroll
    for (int i = 0; i < 4; ++i) av1[i] = ldfrag(&As[cur][(arow + i * 16) * BK + sk1]);
    if (pf) {
      async_ld16(Bgp[0] + ko, &Bs[nxt][(4 * wave + 0) * 512]);
      async_ld16(Bgp[1] + ko, &Bs[nxt][(4 * wave + 1) * 512]);
    }
    asm volatile("" ::: "memory");
    __builtin_amdgcn_s_barrier();
    __builtin_amdgcn_s_setprio(1);
#pragma unroll
    for (int i = 0; i < 4; ++i)
#pragma unroll
      for (int n = 0; n < 4; ++n)
        acc[i][n] = __builtin_amdgcn_mfma_f32_16x16x32_bf16(av0[i], bv0[n], acc[i][n], 0, 0, 0);
    __builtin_amdgcn_s_setprio(0);
    asm volatile("" ::: "memory");
    __builtin_amdgcn_s_barrier();

    // ---- P2 slot: no new reads (R2 already in flight / served) ----
    if (pf) {
      async_ld16(Bgp[2] + ko, &Bs[nxt][(4 * wave + 2) * 512]);
      async_ld16(Bgp[3] + ko, &Bs[nxt][(4 * wave + 3) * 512]);
    }
    asm volatile("" ::: "memory");
    __builtin_amdgcn_s_barrier();
    __builtin_amdgcn_s_setprio(1);
#pragma unroll
    for (int i = 0; i < 4; ++i)
#pragma unroll
      for (int n = 0; n < 4; ++n)
        acc[i][n] = __builtin_amdgcn_mfma_f32_16x16x32_bf16(av1[i], bv1[n], acc[i][n], 0, 0, 0);
    __builtin_amdgcn_s_setprio(0);
    // A-second of tile j (issued P4 of tile j-1 / prologue) must land before
    // the P3-slot reads below; 4 newest (B of tile j+1) stay in flight.
    if (pf) asm volatile("s_waitcnt vmcnt(4)" ::: "memory");
    else    asm volatile("s_waitcnt vmcnt(0)" ::: "memory");
    __builtin_amdgcn_s_barrier();

    // ---- P3 slot: issue R3 (P3 frags) AND R4 (P4 frags) ----
#pragma unroll
    for (int i = 0; i < 4; ++i) av0[i] = ldfrag(&As[cur][(arow + (i + 4) * 16) * BK + sk0]);
#pragma unroll
    for (int i = 0; i < 4; ++i) av1[i] = ldfrag(&As[cur][(arow + (i + 4) * 16) * BK + sk1]);
    if (pf) {
      async_ld16(Agp[0] + ko, &As[nxt][aCh[0] * 512]);
      async_ld16(Agp[1] + ko, &As[nxt][aCh[1] * 512]);
    }
    asm volatile("" ::: "memory");
    __builtin_amdgcn_s_barrier();
    __builtin_amdgcn_s_setprio(1);
#pragma unroll
    for (int i = 0; i < 4; ++i)
#pragma unroll
      for (int n = 0; n < 4; ++n)
        acc[i + 4][n] = __builtin_amdgcn_mfma_f32_16x16x32_bf16(av0[i], bv0[n], acc[i + 4][n], 0, 0, 0);
    __builtin_amdgcn_s_setprio(0);
    asm volatile("" ::: "memory");
    __builtin_amdgcn_s_barrier();

    // ---- P4 slot: no new reads ----
    if (pf) {
      async_ld16(Agp[2] + ko, &As[nxt][aCh[2] * 512]);
      async_ld16(Agp[3] + ko, &As[nxt][aCh[3] * 512]);
    }
    asm volatile("" ::: "memory");
    __builtin_amdgcn_s_barrier();
    __builtin_amdgcn_s_setprio(1);
#pragma unroll
    for (int i = 0; i < 4; ++i)
#pragma unroll
      for (int n = 0; n < 4; ++n)
        acc[i + 4][n] = __builtin_amdgcn_mfma_f32_16x16x32_bf16(av1[i], bv1[n], acc[i + 4][n], 0, 0, 0);
    __builtin_amdgcn_s_setprio(0);
    // B + A-first of tile j+1 must land before next P1-slot reads; A-second
    // (2 newest, issued this phase) stays in flight.
    if (pf) asm volatile("s_waitcnt vmcnt(2)" ::: "memory");
    __builtin_amdgcn_s_barrier();
  }

  // epilogue: C/D layout col = lane&15, row = quad*4 + reg (verified m89/m91)
  const bool isv = (vdst != nullptr) && (by * BN >= 2048);
  if (isv) {
    // fused V-transpose: write vdst[b][vc][t], b = batch, t = row % 2048.
    // Lane's 4 acc rows = 4 consecutive t at fixed vc -> one 8 B store.
    const int b  = bx >> 3;                       // 2048/BM = 8 blocks/batch
    const int t0 = (bx & 7) * BM + wm * 128 + quad * 4;
    u16* vb = vdst + (long long)b * 1024 * 2048;  // C * T
    const int vc0 = by * BN - 2048 + wn * 64 + l16;
#pragma unroll
    for (int j = 0; j < 4; ++j) {
      const int vc = vc0 + j * 16;
      const float bval = bias ? bias[2048 + vc] : 0.0f;
#pragma unroll
      for (int i = 0; i < 8; ++i) {
        u16x4 o;
#pragma unroll
        for (int r = 0; r < 4; ++r) o[r] = f2bf(acc[i][j][r] * scale + bval);
        *(u16x4*)(vb + (long long)vc * 2048 + t0 + i * 16) = o;
      }
    }
  } else {
    const long long row0 = (long long)bx * BM + wm * 128 + quad * 4;
    const int col0 = by * BN + wn * 64 + l16;
#pragma unroll
    for (int j = 0; j < 4; ++j) {
      const int col = col0 + j * 16;
      const float bval = bias ? bias[col] : 0.0f;
#pragma unroll
      for (int i = 0; i < 8; ++i) {
#pragma unroll
        for (int r = 0; r < 4; ++r) {
          const long long row = row0 + i * 16 + r;
          cstore(&Cp[row * ldc + col], acc[i][j][r] * scale + bval);
        }
      }
    }
  }
}

// causal softmax over one row of [T] bf16 scores, in place.
// Thread t owns elements [8t, 8t+8). Reads AND writes only [0, Lw),
// Lw = ceil(L/256)*256 — exactly the range the K-trimmed PV GEMM consumes.
// requires T == 2048
__global__ __launch_bounds__(256)
void softmax_causal(u16* __restrict__ sc, int T)
{
  const int row = blockIdx.x;       // z*T + t
  const int t = row & (T - 1);
  u16* p = sc + (long long)row * T;
  const int L  = t + 1;
  const int Lw = ((t >> 8) + 1) << 8;   // 256-aligned for BM=256 PV trim
  const int tid = threadIdx.x;
  const int lane = tid & 63;
  const int wave = tid >> 6;
  const int base = tid * 8;

  float v[8];
  float m = -1e30f;
  if (base < Lw) {
    const u16x8 in = *(const u16x8*)(p + base);
#pragma unroll
    for (int e = 0; e < 8; ++e) {
      const float f = bf2f(in[e]);
      v[e] = (base + e < L) ? f : -1e30f;
      m = fmaxf(m, v[e]);
    }
  } else {
#pragma unroll
    for (int e = 0; e < 8; ++e) v[e] = -1e30f;
  }
#pragma unroll
  for (int o = 32; o > 0; o >>= 1) m = fmaxf(m, __shfl_xor(m, o, 64));
  __shared__ float redm[4], reds[4];
  if (lane == 0) redm[wave] = m;
  __syncthreads();
  m = fmaxf(fmaxf(redm[0], redm[1]), fmaxf(redm[2], redm[3]));

  float s = 0.0f;
#pragma unroll
  for (int e = 0; e < 8; ++e) {
    const float ex = __expf(v[e] - m);       // v==-1e30 -> 0
    v[e] = (base + e < L) ? ex : 0.0f;
    s += v[e];
  }
#pragma unroll
  for (int o = 32; o > 0; o >>= 1) s += __shfl_xor(s, o, 64);
  if (lane == 0) reds[wave] = s;
  __syncthreads();
  s = reds[0] + reds[1] + reds[2] + reds[3];
  const float inv = 1.0f / s;

  if (base < Lw) {
    u16x8 o8;
#pragma unroll
    for (int e = 0; e < 8; ++e) o8[e] = f2bf(v[e] * inv);
    *(u16x8*)(p + base) = o8;
  }
}

extern "C" void kernel_launch(void* const* d_in, const int* in_sizes, int n_in,
                              void* d_out, int out_size, void* d_ws, size_t ws_size,
                              hipStream_t stream)
{
  (void)in_sizes; (void)n_in; (void)out_size; (void)ws_size;
  const int B = 8, T = 2048, C = 1024;
  const int M = B * T;        // 16384
  const int C3 = 3 * C;       // 3072

  // inputs AND output are FP32 (reference dtypes)
  const float* x     = (const float*)d_in[0];
  const float* Wkqv  = (const float*)d_in[1];
  const float* bkqv  = (const float*)d_in[2];
  const float* Wproj = (const float*)d_in[3];
  const float* bproj = (const float*)d_in[4];
  float* out = (float*)d_out;

  // Workspace: 232 MiB footprint. xb dead after GEMM1; ao aliases it.
  char* w = (char*)d_ws;
  u16* xb     = (u16*)w; w += (size_t)M * C * 2;        // 33.5 MB [M][C]  (aliased by ao)
  u16* WkqvT  = (u16*)w; w += (size_t)C3 * C * 2;       //  6.3 MB [3C][C]
  u16* WprojT = (u16*)w; w += (size_t)C * C * 2;        //  2.1 MB [C][C]
  u16* kqv    = (u16*)w; w += (size_t)M * C3 * 2;       // 100.7 MB [M][3C] (v third unused)
  u16* vT     = (u16*)w; w += (size_t)B * C * T * 2;    // 33.5 MB [B][C][T]
  u16* sc     = (u16*)w; w += (size_t)B * T * T * 2;    // 67.1 MB [B][T][T]
  u16* ao     = xb;                                     // alias: lifetimes disjoint

  dim3 tb(32, 8);

  // x -> bf16
  f32_to_bf16<<<(M * C) / 1024, 256, 0, stream>>>(x, xb);

  // weights -> bf16, NT layout
  transpose_f2b<<<dim3(C3 / 32, C / 32, 1), tb, 0, stream>>>(Wkqv, C3, WkqvT, C);
  transpose_f2b<<<dim3(C / 32, C / 32, 1), tb, 0, stream>>>(Wproj, C, WprojT, C);

  // kqv = x @ W_kqv + b_kqv  [M][3C]. mode 3: N fastest -> A-tile L2 reuse.
  // V third is written TRANSPOSED directly into vT (fused epilogue).
  gemm_nt<u16><<<dim3(C3 / BN, M / BM, 1), 512, 0, stream>>>(
      xb, C, 0, WkqvT, C, 0, kqv, C3, 0, C, bkqv, 1.0f, 3, vT);

  // scores = q @ k^T * (1/sqrt(T)), lower-triangular tiles only
  gemm_nt<u16><<<dim3(T / BM, T / BN, B), 512, 0, stream>>>(
      kqv + C, C3, (long long)T * C3, kqv, C3, (long long)T * C3,
      sc, T, (long long)T * T, C, nullptr, 0.022097086912079608f, 1, nullptr);

  // causal softmax in place
  softmax_causal<<<B * T, 256, 0, stream>>>(sc, T);

  // ao = probs @ v  (NT against vT), K trimmed per tile row; ao aliases xb
  gemm_nt<u16><<<dim3(T / BM, C / BN, B), 512, 0, stream>>>(
      sc, T, (long long)T * T, vT, T, (long long)C * T,
      ao, C, (long long)T * C, T, nullptr, 1.0f, 2, nullptr);

  // out = ao @ W_proj + b_proj   -- FP32 output
  gemm_nt<float><<<dim3(M / BM, C / BN, 1), 512, 0, stream>>>(
      ao, C, 0, WprojT, C, 0, out, C, 0, C, bproj, 1.0f, 0, nullptr);
}

// Round 4
// 446.442 us; speedup vs baseline: 1.3554x; 1.0489x over previous
//
#include <hip/hip_runtime.h>

typedef unsigned short u16;
typedef __attribute__((ext_vector_type(8))) __bf16 bf16x8;
typedef __attribute__((ext_vector_type(8))) unsigned short u16x8;
typedef __attribute__((ext_vector_type(4))) unsigned short u16x4;
typedef __attribute__((ext_vector_type(4))) float f32x4;

#define BM 256
#define BN 256
#define BK 64   // K-step per LDS buffer; double-buffered (128 KiB total)

__device__ __forceinline__ float bf2f(u16 x) {
  union { unsigned int u; float f; } un;
  un.u = ((unsigned int)x) << 16;
  return un.f;
}

__device__ __forceinline__ u16 f2bf(float f) {
  union { float f; unsigned int u; } un;
  un.f = f;
  unsigned int r = un.u + 0x7fffu + ((un.u >> 16) & 1u);
  return (u16)(r >> 16);
}

__device__ __forceinline__ void cstore(u16* p, float v)   { *p = f2bf(v); }
__device__ __forceinline__ void cstore(float* p, float v) { *p = v; }

// async global->LDS, 16B per lane; lds dst is wave-uniform base (HW adds lane*16B)
__device__ __forceinline__ void async_ld16(const u16* g, u16* l) {
  __builtin_amdgcn_global_load_lds(
      (const __attribute__((address_space(1))) unsigned int*)g,
      (__attribute__((address_space(3))) unsigned int*)l, 16, 0, 0);
}

__device__ __forceinline__ bf16x8 ldfrag(const u16* p) {
  union { u16x8 u; bf16x8 b; } c;
  c.u = *(const u16x8*)p;
  return c.b;
}

// ---------------- fp32 -> bf16 elementwise (x), 4 elems/thread ----------------
__global__ __launch_bounds__(256)
void f32_to_bf16(const float* __restrict__ s, u16* __restrict__ d)
{
  const int i = blockIdx.x * 256 + threadIdx.x;
  const float4 v = ((const float4*)s)[i];
  u16x4 o;
  o.x = f2bf(v.x); o.y = f2bf(v.y); o.z = f2bf(v.z); o.w = f2bf(v.w);
  ((u16x4*)d)[i] = o;
}

// ---------------- fp32 [R][CC] -> bf16 transposed [CC][R] ----------------
__global__ __launch_bounds__(256)
void transpose_f2b(const float* __restrict__ src, int sld,
                   u16* __restrict__ dst, int dld)
{
  __shared__ float tile[32][33];
  const int c0 = blockIdx.x * 32;
  const int r0 = blockIdx.y * 32;
  const int tx = threadIdx.x;   // 0..31
  const int ty = threadIdx.y;   // 0..7
#pragma unroll
  for (int i = ty; i < 32; i += 8)
    tile[i][tx] = src[(long long)(r0 + i) * sld + c0 + tx];
  __syncthreads();
#pragma unroll
  for (int i = ty; i < 32; i += 8)
    dst[(long long)(c0 + i) * dld + r0 + tx] = f2bf(tile[tx][i]);
}

// C[M][N] = A[M][K] * Bt[N][K]^T  (NT GEMM), bf16 in, fp32 accum, OT out.
// 256x256 tile, BK=64 double-buffered (128 KiB LDS), 8 waves (2M x 4N,
// 128x64 out/wave), 4 phases/K-tile, 16 MFMA each. Register-pipelined frag
// reads: P1 slot issues P1+P2 fragments (16 ds_read_b128), P3 slot issues
// P3+P4 (8) — R2/R4 are served by the LDS FIFO under the P1/P3 MFMA bursts.
// Staging ledger (verified r2/r3):
//   stage B01@P1, B23@P2, A01@P3, A23@P4 (for tile j+1)
//   end-P2: vmcnt(4)  -> A23 of tile j landed (needed by P3-slot reads)
//   end-P4: vmcnt(2)  -> B01,B23,A01 of tile j+1 landed (needed by next P1)
// LDS bank swizzle (slot ^= row&7 on 16B slots), both-sides rule: linear
// global_load_lds dest + inverse-permuted global src + XOR'd ds_read.
// T1 XCD swizzle: flat block id chunked so each XCD owns a contiguous range
// (bijective since all grids are %8==0) -> operand-panel reuse stays in one
// XCD's L2 instead of being round-robined across 8 incoherent L2s.
// mode 0: plain; mode 1: causal skip; mode 2: K trimmed to (bx+1)*BM;
// mode 3: plain, swapped block decode (x=N fastest -> A-tile reuse).
// kEnd must be a multiple of 64.
// vdst != nullptr: blocks with N-base >= 2048 write u16 output TRANSPOSED
// into vdst[b][col-2048][row%2048] (fused V-transpose for the kqv GEMM).
template <typename OT>
__global__ __launch_bounds__(512, 2)
void gemm_nt(const u16* __restrict__ A, int lda, long long sA,
             const u16* __restrict__ Bt, int ldb, long long sB,
             OT* __restrict__ Cp, int ldc, long long sC,
             int K, const float* __restrict__ bias, float scale, int mode,
             u16* __restrict__ vdst)
{
  // ---- T1: XCD-chunked bijective block swizzle (requires nwg % 8 == 0) ----
  const int gx = gridDim.x, gy = gridDim.y;
  const int nwg  = gx * gy * gridDim.z;
  const int flat = blockIdx.x + gx * (blockIdx.y + gy * blockIdx.z);
  const int qch  = nwg >> 3;
  const int swzf = (flat & 7) * qch + (flat >> 3);
  int bx = swzf % gx;
  const int rem = swzf / gx;
  int by = rem % gy;
  const int bz = rem / gy;
  if (mode == 3) { const int t2 = bx; bx = by; by = t2; }
  if (mode == 1 && by > bx) return;
  A  += (long long)bz * sA;
  Bt += (long long)bz * sB;
  Cp += (long long)bz * sC;
  int kEnd = K;
  if (mode == 2) { int ke = (bx + 1) * BM; kEnd = ke < K ? ke : K; }

  __shared__ __align__(16) u16 As[2][BM * BK];
  __shared__ __align__(16) u16 Bs[2][BM * BK];

  const int tid  = threadIdx.x;
  const int wave = tid >> 6;      // 0..7
  const int lane = tid & 63;
  const int l16  = lane & 15;
  const int quad = lane >> 4;     // 0..3
  const int wm = wave >> 2;       // 0..1 -> rows wm*128..+127
  const int wn = wave & 3;        // 0..3 -> cols wn*64..+63

  // ds_read slot (16B units) = (kk*4+quad) ^ (row&7); row&7 == l16&7.
  const int sk0 = ((quad    ) ^ (l16 & 7)) * 8;   // kk = 0
  const int sk1 = ((quad + 4) ^ (l16 & 7)) * 8;   // kk = 1
  const int arow = wm * 128 + l16;
  const int brow = wn * 64  + l16;

  // staging: chunk = 1 KiB = 8 rows x 64 cols; lane l -> row chunk*8+(l>>3),
  // slot l&7; source col = swizzle-inverse ((l&7)^(l>>3))*8 elems.
  const int srow8 = lane >> 3;
  const int sx    = ((lane & 7) ^ srow8) * 8;

  // wave w stages B chunks {4w..4w+3}; A chunks: first-half {f0,f0+1},
  // second-half {f0+8,f0+9}.
  const int f0 = (wave < 4) ? (2 * wave) : (16 + 2 * (wave - 4));
  const int aCh[4] = { f0, f0 + 1, f0 + 8, f0 + 9 };

  const u16* Bgp[4];
#pragma unroll
  for (int p = 0; p < 4; ++p)
    Bgp[p] = Bt + (long long)(by * BN + (4 * wave + p) * 8 + srow8) * ldb + sx;
  const u16* Agp[4];
#pragma unroll
  for (int q = 0; q < 4; ++q)
    Agp[q] = A + (long long)(bx * BM + aCh[q] * 8 + srow8) * lda + sx;

  f32x4 zero4;
  zero4.x = zero4.y = zero4.z = zero4.w = 0.0f;
  f32x4 acc[8][4];
#pragma unroll
  for (int i = 0; i < 8; ++i)
#pragma unroll
    for (int j = 0; j < 4; ++j) acc[i][j] = zero4;

  const int nt = kEnd / BK;

  // prologue: tile 0 -> buf 0; order B0-3, A0-3; vmcnt(2) leaves A-second
  // (aCh[2],aCh[3]) in flight -- landed by end-P2's vmcnt(4).
#pragma unroll
  for (int p = 0; p < 4; ++p) async_ld16(Bgp[p], &Bs[0][(4 * wave + p) * 512]);
#pragma unroll
  for (int q = 0; q < 4; ++q) async_ld16(Agp[q], &As[0][aCh[q] * 512]);
  asm volatile("s_waitcnt vmcnt(2)" ::: "memory");
  __builtin_amdgcn_s_barrier();

  for (int j = 0; j < nt; ++j) {
    const int cur = j & 1;
    const int nxt = cur ^ 1;
    const bool pf = (j + 1 < nt);
    const int ko = (j + 1) * BK;

    bf16x8 bv0[4], bv1[4], av0[4], av1[4];

    // ---- P1 slot: issue R1 (P1 frags) AND R2 (P2 frags) ----
#pragma unroll
    for (int n = 0; n < 4; ++n) bv0[n] = ldfrag(&Bs[cur][(brow + n * 16) * BK + sk0]);
#pragma unroll
    for (int i = 0; i < 4; ++i) av0[i] = ldfrag(&As[cur][(arow + i * 16) * BK + sk0]);
#pragma unroll
    for (int n = 0; n < 4; ++n) bv1[n] = ldfrag(&Bs[cur][(brow + n * 16) * BK + sk1]);
#pragma unroll
    for (int i = 0; i < 4; ++i) av1[i] = ldfrag(&As[cur][(arow + i * 16) * BK + sk1]);
    if (pf) {
      async_ld16(Bgp[0] + ko, &Bs[nxt][(4 * wave + 0) * 512]);
      async_ld16(Bgp[1] + ko, &Bs[nxt][(4 * wave + 1) * 512]);
    }
    asm volatile("" ::: "memory");
    __builtin_amdgcn_s_barrier();
    __builtin_amdgcn_s_setprio(1);
#pragma unroll
    for (int i = 0; i < 4; ++i)
#pragma unroll
      for (int n = 0; n < 4; ++n)
        acc[i][n] = __builtin_amdgcn_mfma_f32_16x16x32_bf16(av0[i], bv0[n], acc[i][n], 0, 0, 0);
    __builtin_amdgcn_s_setprio(0);
    asm volatile("" ::: "memory");
    __builtin_amdgcn_s_barrier();

    // ---- P2 slot: no new reads (R2 already in flight / served) ----
    if (pf) {
      async_ld16(Bgp[2] + ko, &Bs[nxt][(4 * wave + 2) * 512]);
      async_ld16(Bgp[3] + ko, &Bs[nxt][(4 * wave + 3) * 512]);
    }
    asm volatile("" ::: "memory");
    __builtin_amdgcn_s_barrier();
    __builtin_amdgcn_s_setprio(1);
#pragma unroll
    for (int i = 0; i < 4; ++i)
#pragma unroll
      for (int n = 0; n < 4; ++n)
        acc[i][n] = __builtin_amdgcn_mfma_f32_16x16x32_bf16(av1[i], bv1[n], acc[i][n], 0, 0, 0);
    __builtin_amdgcn_s_setprio(0);
    // A-second of tile j (issued P4 of tile j-1 / prologue) must land before
    // the P3-slot reads below; 4 newest (B of tile j+1) stay in flight.
    if (pf) asm volatile("s_waitcnt vmcnt(4)" ::: "memory");
    else    asm volatile("s_waitcnt vmcnt(0)" ::: "memory");
    __builtin_amdgcn_s_barrier();

    // ---- P3 slot: issue R3 (P3 frags) AND R4 (P4 frags) ----
#pragma unroll
    for (int i = 0; i < 4; ++i) av0[i] = ldfrag(&As[cur][(arow + (i + 4) * 16) * BK + sk0]);
#pragma unroll
    for (int i = 0; i < 4; ++i) av1[i] = ldfrag(&As[cur][(arow + (i + 4) * 16) * BK + sk1]);
    if (pf) {
      async_ld16(Agp[0] + ko, &As[nxt][aCh[0] * 512]);
      async_ld16(Agp[1] + ko, &As[nxt][aCh[1] * 512]);
    }
    asm volatile("" ::: "memory");
    __builtin_amdgcn_s_barrier();
    __builtin_amdgcn_s_setprio(1);
#pragma unroll
    for (int i = 0; i < 4; ++i)
#pragma unroll
      for (int n = 0; n < 4; ++n)
        acc[i + 4][n] = __builtin_amdgcn_mfma_f32_16x16x32_bf16(av0[i], bv0[n], acc[i + 4][n], 0, 0, 0);
    __builtin_amdgcn_s_setprio(0);
    asm volatile("" ::: "memory");
    __builtin_amdgcn_s_barrier();

    // ---- P4 slot: no new reads ----
    if (pf) {
      async_ld16(Agp[2] + ko, &As[nxt][aCh[2] * 512]);
      async_ld16(Agp[3] + ko, &As[nxt][aCh[3] * 512]);
    }
    asm volatile("" ::: "memory");
    __builtin_amdgcn_s_barrier();
    __builtin_amdgcn_s_setprio(1);
#pragma unroll
    for (int i = 0; i < 4; ++i)
#pragma unroll
      for (int n = 0; n < 4; ++n)
        acc[i + 4][n] = __builtin_amdgcn_mfma_f32_16x16x32_bf16(av1[i], bv1[n], acc[i + 4][n], 0, 0, 0);
    __builtin_amdgcn_s_setprio(0);
    // B + A-first of tile j+1 must land before next P1-slot reads; A-second
    // (2 newest, issued this phase) stays in flight.
    if (pf) asm volatile("s_waitcnt vmcnt(2)" ::: "memory");
    __builtin_amdgcn_s_barrier();
  }

  // epilogue: C/D layout col = lane&15, row = quad*4 + reg (verified m89/m91)
  const bool isv = (vdst != nullptr) && (by * BN >= 2048);
  if (isv) {
    // fused V-transpose: write vdst[b][vc][t], b = batch, t = row % 2048.
    // Lane's 4 acc rows = 4 consecutive t at fixed vc -> one 8 B store.
    const int b  = bx >> 3;                       // 2048/BM = 8 blocks/batch
    const int t0 = (bx & 7) * BM + wm * 128 + quad * 4;
    u16* vb = vdst + (long long)b * 1024 * 2048;  // C * T
    const int vc0 = by * BN - 2048 + wn * 64 + l16;
#pragma unroll
    for (int j = 0; j < 4; ++j) {
      const int vc = vc0 + j * 16;
      const float bval = bias ? bias[2048 + vc] : 0.0f;
#pragma unroll
      for (int i = 0; i < 8; ++i) {
        u16x4 o;
#pragma unroll
        for (int r = 0; r < 4; ++r) o[r] = f2bf(acc[i][j][r] * scale + bval);
        *(u16x4*)(vb + (long long)vc * 2048 + t0 + i * 16) = o;
      }
    }
  } else {
    const long long row0 = (long long)bx * BM + wm * 128 + quad * 4;
    const int col0 = by * BN + wn * 64 + l16;
#pragma unroll
    for (int j = 0; j < 4; ++j) {
      const int col = col0 + j * 16;
      const float bval = bias ? bias[col] : 0.0f;
#pragma unroll
      for (int i = 0; i < 8; ++i) {
#pragma unroll
        for (int r = 0; r < 4; ++r) {
          const long long row = row0 + i * 16 + r;
          cstore(&Cp[row * ldc + col], acc[i][j][r] * scale + bval);
        }
      }
    }
  }
}

// causal softmax over one row of [T] bf16 scores, in place.
// Thread t owns elements [8t, 8t+8). Reads AND writes only [0, Lw),
// Lw = ceil(L/256)*256 — exactly the range the K-trimmed PV GEMM consumes.
// requires T == 2048
__global__ __launch_bounds__(256)
void softmax_causal(u16* __restrict__ sc, int T)
{
  const int row = blockIdx.x;       // z*T + t
  const int t = row & (T - 1);
  u16* p = sc + (long long)row * T;
  const int L  = t + 1;
  const int Lw = ((t >> 8) + 1) << 8;   // 256-aligned for BM=256 PV trim
  const int tid = threadIdx.x;
  const int lane = tid & 63;
  const int wave = tid >> 6;
  const int base = tid * 8;

  float v[8];
  float m = -1e30f;
  if (base < Lw) {
    const u16x8 in = *(const u16x8*)(p + base);
#pragma unroll
    for (int e = 0; e < 8; ++e) {
      const float f = bf2f(in[e]);
      v[e] = (base + e < L) ? f : -1e30f;
      m = fmaxf(m, v[e]);
    }
  } else {
#pragma unroll
    for (int e = 0; e < 8; ++e) v[e] = -1e30f;
  }
#pragma unroll
  for (int o = 32; o > 0; o >>= 1) m = fmaxf(m, __shfl_xor(m, o, 64));
  __shared__ float redm[4], reds[4];
  if (lane == 0) redm[wave] = m;
  __syncthreads();
  m = fmaxf(fmaxf(redm[0], redm[1]), fmaxf(redm[2], redm[3]));

  float s = 0.0f;
#pragma unroll
  for (int e = 0; e < 8; ++e) {
    const float ex = __expf(v[e] - m);       // v==-1e30 -> 0
    v[e] = (base + e < L) ? ex : 0.0f;
    s += v[e];
  }
#pragma unroll
  for (int o = 32; o > 0; o >>= 1) s += __shfl_xor(s, o, 64);
  if (lane == 0) reds[wave] = s;
  __syncthreads();
  s = reds[0] + reds[1] + reds[2] + reds[3];
  const float inv = 1.0f / s;

  if (base < Lw) {
    u16x8 o8;
#pragma unroll
    for (int e = 0; e < 8; ++e) o8[e] = f2bf(v[e] * inv);
    *(u16x8*)(p + base) = o8;
  }
}

extern "C" void kernel_launch(void* const* d_in, const int* in_sizes, int n_in,
                              void* d_out, int out_size, void* d_ws, size_t ws_size,
                              hipStream_t stream)
{
  (void)in_sizes; (void)n_in; (void)out_size; (void)ws_size;
  const int B = 8, T = 2048, C = 1024;
  const int M = B * T;        // 16384
  const int C3 = 3 * C;       // 3072

  // inputs AND output are FP32 (reference dtypes)
  const float* x     = (const float*)d_in[0];
  const float* Wkqv  = (const float*)d_in[1];
  const float* bkqv  = (const float*)d_in[2];
  const float* Wproj = (const float*)d_in[3];
  const float* bproj = (const float*)d_in[4];
  float* out = (float*)d_out;

  // Workspace: 232 MiB footprint. xb dead after GEMM1; ao aliases it.
  char* w = (char*)d_ws;
  u16* xb     = (u16*)w; w += (size_t)M * C * 2;        // 33.5 MB [M][C]  (aliased by ao)
  u16* WkqvT  = (u16*)w; w += (size_t)C3 * C * 2;       //  6.3 MB [3C][C]
  u16* WprojT = (u16*)w; w += (size_t)C * C * 2;        //  2.1 MB [C][C]
  u16* kqv    = (u16*)w; w += (size_t)M * C3 * 2;       // 100.7 MB [M][3C] (v third unused)
  u16* vT     = (u16*)w; w += (size_t)B * C * T * 2;    // 33.5 MB [B][C][T]
  u16* sc     = (u16*)w; w += (size_t)B * T * T * 2;    // 67.1 MB [B][T][T]
  u16* ao     = xb;                                     // alias: lifetimes disjoint

  dim3 tb(32, 8);

  // x -> bf16
  f32_to_bf16<<<(M * C) / 1024, 256, 0, stream>>>(x, xb);

  // weights -> bf16, NT layout
  transpose_f2b<<<dim3(C3 / 32, C / 32, 1), tb, 0, stream>>>(Wkqv, C3, WkqvT, C);
  transpose_f2b<<<dim3(C / 32, C / 32, 1), tb, 0, stream>>>(Wproj, C, WprojT, C);

  // kqv = x @ W_kqv + b_kqv  [M][3C]. mode 3: N fastest -> A-tile L2 reuse;
  // T1 swizzle gives each XCD 8 M-rows x all 12 N (A set = 4 MB = one L2).
  // V third is written TRANSPOSED directly into vT (fused epilogue).
  gemm_nt<u16><<<dim3(C3 / BN, M / BM, 1), 512, 0, stream>>>(
      xb, C, 0, WkqvT, C, 0, kqv, C3, 0, C, bkqv, 1.0f, 3, vT);

  // scores = q @ k^T * (1/sqrt(T)), lower-triangular tiles only
  // (T1 swizzle chunk = 64 blocks = exactly one batch per XCD)
  gemm_nt<u16><<<dim3(T / BM, T / BN, B), 512, 0, stream>>>(
      kqv + C, C3, (long long)T * C3, kqv, C3, (long long)T * C3,
      sc, T, (long long)T * T, C, nullptr, 0.022097086912079608f, 1, nullptr);

  // causal softmax in place
  softmax_causal<<<B * T, 256, 0, stream>>>(sc, T);

  // ao = probs @ v  (NT against vT), K trimmed per tile row; ao aliases xb
  // (T1 swizzle chunk = 32 blocks = one batch per XCD)
  gemm_nt<u16><<<dim3(T / BM, C / BN, B), 512, 0, stream>>>(
      sc, T, (long long)T * T, vT, T, (long long)C * T,
      ao, C, (long long)T * C, T, nullptr, 1.0f, 2, nullptr);

  // out = ao @ W_proj + b_proj   -- FP32 output. mode 3 (grid x=N fastest)
  // so the 4 N-blocks sharing an A-tile are adjacent -> same XCD after T1.
  gemm_nt<float><<<dim3(C / BN, M / BM, 1), 512, 0, stream>>>(
      ao, C, 0, WprojT, C, 0, out, C, 0, C, bproj, 1.0f, 3, nullptr);
}

// Round 6
// 438.044 us; speedup vs baseline: 1.3813x; 1.0192x over previous
//
#include <hip/hip_runtime.h>

typedef unsigned short u16;
typedef __attribute__((ext_vector_type(8))) __bf16 bf16x8;
typedef __attribute__((ext_vector_type(8))) unsigned short u16x8;
typedef __attribute__((ext_vector_type(4))) unsigned short u16x4;
typedef __attribute__((ext_vector_type(4))) float f32x4;

#define BM 256
#define BN 256
#define BK 64   // K-step per LDS buffer; double-buffered (128 KiB total)

__device__ __forceinline__ float bf2f(u16 x) {
  union { unsigned int u; float f; } un;
  un.u = ((unsigned int)x) << 16;
  return un.f;
}

__device__ __forceinline__ u16 f2bf(float f) {
  union { float f; unsigned int u; } un;
  un.f = f;
  unsigned int r = un.u + 0x7fffu + ((un.u >> 16) & 1u);
  return (u16)(r >> 16);
}

__device__ __forceinline__ void cstore(u16* p, float v)   { *p = f2bf(v); }
__device__ __forceinline__ void cstore(float* p, float v) { *p = v; }

// async global->LDS, 16B per lane; lds dst is wave-uniform base (HW adds lane*16B)
__device__ __forceinline__ void async_ld16(const u16* g, u16* l) {
  __builtin_amdgcn_global_load_lds(
      (const __attribute__((address_space(1))) unsigned int*)g,
      (__attribute__((address_space(3))) unsigned int*)l, 16, 0, 0);
}

__device__ __forceinline__ bf16x8 ldfrag(const u16* p) {
  union { u16x8 u; bf16x8 b; } c;
  c.u = *(const u16x8*)p;
  return c.b;
}

// ---------------- fp32 -> bf16 elementwise (x), 4 elems/thread ----------------
__global__ __launch_bounds__(256)
void f32_to_bf16(const float* __restrict__ s, u16* __restrict__ d)
{
  const int i = blockIdx.x * 256 + threadIdx.x;
  const float4 v = ((const float4*)s)[i];
  u16x4 o;
  o.x = f2bf(v.x); o.y = f2bf(v.y); o.z = f2bf(v.z); o.w = f2bf(v.w);
  ((u16x4*)d)[i] = o;
}

// ---------------- fp32 [R][CC] -> bf16 transposed [CC][R] ----------------
__global__ __launch_bounds__(256)
void transpose_f2b(const float* __restrict__ src, int sld,
                   u16* __restrict__ dst, int dld)
{
  __shared__ float tile[32][33];
  const int c0 = blockIdx.x * 32;
  const int r0 = blockIdx.y * 32;
  const int tx = threadIdx.x;   // 0..31
  const int ty = threadIdx.y;   // 0..7
#pragma unroll
  for (int i = ty; i < 32; i += 8)
    tile[i][tx] = src[(long long)(r0 + i) * sld + c0 + tx];
  __syncthreads();
#pragma unroll
  for (int i = ty; i < 32; i += 8)
    dst[(long long)(c0 + i) * dld + r0 + tx] = f2bf(tile[tx][i]);
}

// C[M][N] = A[M][K] * Bt[N][K]^T  (NT GEMM), bf16 in, fp32 accum, OT out.
// 256x256 tile, BK=64 double-buffered (128 KiB LDS), 8 waves (2M x 4N,
// 128x64 out/wave), 4 phases/K-tile, 16 MFMA each. Register-pipelined frag
// reads: P1 slot issues P1+P2 fragments (16 ds_read_b128), P3 slot issues
// P3+P4 (8) — R2/R4 are served by the LDS FIFO under the P1/P3 MFMA bursts
// (compiler emits counted lgkmcnt, so P1's burst waits only its own 8).
// Staging ledger (r5: DEEP-SLACK — every wait covers >= 3 phases ~1900 cyc,
// above worst-case HBM latency; never drain to 0 in steady state):
//   P1 slot: issue B01,B23,A01 of tile j+1   (6 loads)
//   P3 slot: issue A23 of tile j+1            (2 loads)
//   end-P2: vmcnt(6) -> A23 of tile j landed (issued P3 of j-1, 3-ph slack)
//   end-P4: vmcnt(2) -> B01,B23,A01 of tile j+1 landed (issued P1, 3-ph slack)
// LDS bank swizzle (slot ^= row&7 on 16B slots), both-sides rule: linear
// global_load_lds dest + inverse-permuted global src + XOR'd ds_read.
// T1 XCD swizzle: flat block id chunked so each XCD owns a contiguous range
// (bijective since all grids are %8==0).
// mode 0: plain; mode 1: causal skip; mode 2: K trimmed to (bx+1)*BM;
// mode 3: plain, swapped block decode (x=N fastest -> A-tile reuse).
// kEnd must be a multiple of 64.
// vdst != nullptr: blocks with N-base >= 2048 write u16 output TRANSPOSED
// into vdst[b][col-2048][row%2048] (fused V-transpose for the kqv GEMM).
template <typename OT>
__global__ __launch_bounds__(512, 2)
void gemm_nt(const u16* __restrict__ A, int lda, long long sA,
             const u16* __restrict__ Bt, int ldb, long long sB,
             OT* __restrict__ Cp, int ldc, long long sC,
             int K, const float* __restrict__ bias, float scale, int mode,
             u16* __restrict__ vdst)
{
  // ---- T1: XCD-chunked bijective block swizzle (requires nwg % 8 == 0) ----
  const int gx = gridDim.x, gy = gridDim.y;
  const int nwg  = gx * gy * gridDim.z;
  const int flat = blockIdx.x + gx * (blockIdx.y + gy * blockIdx.z);
  const int qch  = nwg >> 3;
  const int swzf = (flat & 7) * qch + (flat >> 3);
  int bx = swzf % gx;
  const int rem = swzf / gx;
  int by = rem % gy;
  const int bz = rem / gy;
  if (mode == 3) { const int t2 = bx; bx = by; by = t2; }
  if (mode == 1 && by > bx) return;
  A  += (long long)bz * sA;
  Bt += (long long)bz * sB;
  Cp += (long long)bz * sC;
  int kEnd = K;
  if (mode == 2) { int ke = (bx + 1) * BM; kEnd = ke < K ? ke : K; }

  __shared__ __align__(16) u16 As[2][BM * BK];
  __shared__ __align__(16) u16 Bs[2][BM * BK];

  const int tid  = threadIdx.x;
  const int wave = tid >> 6;      // 0..7
  const int lane = tid & 63;
  const int l16  = lane & 15;
  const int quad = lane >> 4;     // 0..3
  const int wm = wave >> 2;       // 0..1 -> rows wm*128..+127
  const int wn = wave & 3;        // 0..3 -> cols wn*64..+63

  // ds_read slot (16B units) = (kk*4+quad) ^ (row&7); row&7 == l16&7.
  const int sk0 = ((quad    ) ^ (l16 & 7)) * 8;   // kk = 0
  const int sk1 = ((quad + 4) ^ (l16 & 7)) * 8;   // kk = 1
  const int arow = wm * 128 + l16;
  const int brow = wn * 64  + l16;

  // staging: chunk = 1 KiB = 8 rows x 64 cols; lane l -> row chunk*8+(l>>3),
  // slot l&7; source col = swizzle-inverse ((l&7)^(l>>3))*8 elems.
  const int srow8 = lane >> 3;
  const int sx    = ((lane & 7) ^ srow8) * 8;

  // wave w stages B chunks {4w..4w+3}; A chunks: first-half {f0,f0+1},
  // second-half {f0+8,f0+9}.
  const int f0 = (wave < 4) ? (2 * wave) : (16 + 2 * (wave - 4));
  const int aCh[4] = { f0, f0 + 1, f0 + 8, f0 + 9 };

  const u16* Bgp[4];
#pragma unroll
  for (int p = 0; p < 4; ++p)
    Bgp[p] = Bt + (long long)(by * BN + (4 * wave + p) * 8 + srow8) * ldb + sx;
  const u16* Agp[4];
#pragma unroll
  for (int q = 0; q < 4; ++q)
    Agp[q] = A + (long long)(bx * BM + aCh[q] * 8 + srow8) * lda + sx;

  f32x4 zero4;
  zero4.x = zero4.y = zero4.z = zero4.w = 0.0f;
  f32x4 acc[8][4];
#pragma unroll
  for (int i = 0; i < 8; ++i)
#pragma unroll
    for (int j = 0; j < 4; ++j) acc[i][j] = zero4;

  const int nt = kEnd / BK;

  // prologue: tile 0 -> buf 0; order B0-3, A01, A23 (A23 newest — matches
  // steady-state invariant); vmcnt(2) leaves A23 in flight (landed by
  // end-P2's vmcnt(6)).
#pragma unroll
  for (int p = 0; p < 4; ++p) async_ld16(Bgp[p], &Bs[0][(4 * wave + p) * 512]);
#pragma unroll
  for (int q = 0; q < 4; ++q) async_ld16(Agp[q], &As[0][aCh[q] * 512]);
  asm volatile("s_waitcnt vmcnt(2)" ::: "memory");
  __builtin_amdgcn_s_barrier();

  for (int j = 0; j < nt; ++j) {
    const int cur = j & 1;
    const int nxt = cur ^ 1;
    const bool pf = (j + 1 < nt);
    const int ko = (j + 1) * BK;

    bf16x8 bv0[4], bv1[4], av0[4], av1[4];

    // ---- P1 slot: issue R1+R2 frags; stage B01,B23,A01 of tile j+1 ----
#pragma unroll
    for (int n = 0; n < 4; ++n) bv0[n] = ldfrag(&Bs[cur][(brow + n * 16) * BK + sk0]);
#pragma unroll
    for (int i = 0; i < 4; ++i) av0[i] = ldfrag(&As[cur][(arow + i * 16) * BK + sk0]);
#pragma unroll
    for (int n = 0; n < 4; ++n) bv1[n] = ldfrag(&Bs[cur][(brow + n * 16) * BK + sk1]);
#pragma unroll
    for (int i = 0; i < 4; ++i) av1[i] = ldfrag(&As[cur][(arow + i * 16) * BK + sk1]);
    if (pf) {
      async_ld16(Bgp[0] + ko, &Bs[nxt][(4 * wave + 0) * 512]);
      async_ld16(Bgp[1] + ko, &Bs[nxt][(4 * wave + 1) * 512]);
      async_ld16(Bgp[2] + ko, &Bs[nxt][(4 * wave + 2) * 512]);
      async_ld16(Bgp[3] + ko, &Bs[nxt][(4 * wave + 3) * 512]);
      async_ld16(Agp[0] + ko, &As[nxt][aCh[0] * 512]);
      async_ld16(Agp[1] + ko, &As[nxt][aCh[1] * 512]);
    }
    asm volatile("" ::: "memory");
    __builtin_amdgcn_s_barrier();
    __builtin_amdgcn_s_setprio(1);
#pragma unroll
    for (int i = 0; i < 4; ++i)
#pragma unroll
      for (int n = 0; n < 4; ++n)
        acc[i][n] = __builtin_amdgcn_mfma_f32_16x16x32_bf16(av0[i], bv0[n], acc[i][n], 0, 0, 0);
    __builtin_amdgcn_s_setprio(0);
    asm volatile("" ::: "memory");
    __builtin_amdgcn_s_barrier();

    // ---- P2 slot: no new reads, no new stages ----
    __builtin_amdgcn_s_setprio(1);
#pragma unroll
    for (int i = 0; i < 4; ++i)
#pragma unroll
      for (int n = 0; n < 4; ++n)
        acc[i][n] = __builtin_amdgcn_mfma_f32_16x16x32_bf16(av1[i], bv1[n], acc[i][n], 0, 0, 0);
    __builtin_amdgcn_s_setprio(0);
    // A23 of tile j must land before P3-slot reads. It was issued at P3 of
    // tile j-1 (3-phase slack). The 6 tile-j+1 loads issued at P1 stay out.
    if (pf) asm volatile("s_waitcnt vmcnt(6)" ::: "memory");
    else    asm volatile("s_waitcnt vmcnt(0)" ::: "memory");
    __builtin_amdgcn_s_barrier();

    // ---- P3 slot: issue R3+R4 frags; stage A23 of tile j+1 ----
#pragma unroll
    for (int i = 0; i < 4; ++i) av0[i] = ldfrag(&As[cur][(arow + (i + 4) * 16) * BK + sk0]);
#pragma unroll
    for (int i = 0; i < 4; ++i) av1[i] = ldfrag(&As[cur][(arow + (i + 4) * 16) * BK + sk1]);
    if (pf) {
      async_ld16(Agp[2] + ko, &As[nxt][aCh[2] * 512]);
      async_ld16(Agp[3] + ko, &As[nxt][aCh[3] * 512]);
    }
    asm volatile("" ::: "memory");
    __builtin_amdgcn_s_barrier();
    __builtin_amdgcn_s_setprio(1);
#pragma unroll
    for (int i = 0; i < 4; ++i)
#pragma unroll
      for (int n = 0; n < 4; ++n)
        acc[i + 4][n] = __builtin_amdgcn_mfma_f32_16x16x32_bf16(av0[i], bv0[n], acc[i + 4][n], 0, 0, 0);
    __builtin_amdgcn_s_setprio(0);
    asm volatile("" ::: "memory");
    __builtin_amdgcn_s_barrier();

    // ---- P4 slot: no new reads, no new stages ----
    __builtin_amdgcn_s_setprio(1);
#pragma unroll
    for (int i = 0; i < 4; ++i)
#pragma unroll
      for (int n = 0; n < 4; ++n)
        acc[i + 4][n] = __builtin_amdgcn_mfma_f32_16x16x32_bf16(av1[i], bv1[n], acc[i + 4][n], 0, 0, 0);
    __builtin_amdgcn_s_setprio(0);
    // B01,B23,A01 of tile j+1 must land before next P1-slot reads (issued at
    // P1 of this tile, 3-phase slack). A23 (2 newest) stays in flight.
    if (pf) asm volatile("s_waitcnt vmcnt(2)" ::: "memory");
    __builtin_amdgcn_s_barrier();
  }

  // epilogue: C/D layout col = lane&15, row = quad*4 + reg (verified m89/m91)
  const bool isv = (vdst != nullptr) && (by * BN >= 2048);
  if (isv) {
    // fused V-transpose: write vdst[b][vc][t], b = batch, t = row % 2048.
    // Lane's 4 acc rows = 4 consecutive t at fixed vc -> one 8 B store.
    const int b  = bx >> 3;                       // 2048/BM = 8 blocks/batch
    const int t0 = (bx & 7) * BM + wm * 128 + quad * 4;
    u16* vb = vdst + (long long)b * 1024 * 2048;  // C * T
    const int vc0 = by * BN - 2048 + wn * 64 + l16;
#pragma unroll
    for (int j = 0; j < 4; ++j) {
      const int vc = vc0 + j * 16;
      const float bval = bias ? bias[2048 + vc] : 0.0f;
#pragma unroll
      for (int i = 0; i < 8; ++i) {
        u16x4 o;
#pragma unroll
        for (int r = 0; r < 4; ++r) o[r] = f2bf(acc[i][j][r] * scale + bval);
        *(u16x4*)(vb + (long long)vc * 2048 + t0 + i * 16) = o;
      }
    }
  } else {
    const long long row0 = (long long)bx * BM + wm * 128 + quad * 4;
    const int col0 = by * BN + wn * 64 + l16;
#pragma unroll
    for (int j = 0; j < 4; ++j) {
      const int col = col0 + j * 16;
      const float bval = bias ? bias[col] : 0.0f;
#pragma unroll
      for (int i = 0; i < 8; ++i) {
#pragma unroll
        for (int r = 0; r < 4; ++r) {
          const long long row = row0 + i * 16 + r;
          cstore(&Cp[row * ldc + col], acc[i][j][r] * scale + bval);
        }
      }
    }
  }
}

// causal softmax over one row of [T] bf16 scores, in place.
// Thread t owns elements [8t, 8t+8). Reads AND writes only [0, Lw),
// Lw = ceil(L/256)*256 — exactly the range the K-trimmed PV GEMM consumes.
// requires T == 2048
__global__ __launch_bounds__(256)
void softmax_causal(u16* __restrict__ sc, int T)
{
  const int row = blockIdx.x;       // z*T + t
  const int t = row & (T - 1);
  u16* p = sc + (long long)row * T;
  const int L  = t + 1;
  const int Lw = ((t >> 8) + 1) << 8;   // 256-aligned for BM=256 PV trim
  const int tid = threadIdx.x;
  const int lane = tid & 63;
  const int wave = tid >> 6;
  const int base = tid * 8;

  float v[8];
  float m = -1e30f;
  if (base < Lw) {
    const u16x8 in = *(const u16x8*)(p + base);
#pragma unroll
    for (int e = 0; e < 8; ++e) {
      const float f = bf2f(in[e]);
      v[e] = (base + e < L) ? f : -1e30f;
      m = fmaxf(m, v[e]);
    }
  } else {
#pragma unroll
    for (int e = 0; e < 8; ++e) v[e] = -1e30f;
  }
#pragma unroll
  for (int o = 32; o > 0; o >>= 1) m = fmaxf(m, __shfl_xor(m, o, 64));
  __shared__ float redm[4], reds[4];
  if (lane == 0) redm[wave] = m;
  __syncthreads();
  m = fmaxf(fmaxf(redm[0], redm[1]), fmaxf(redm[2], redm[3]));

  float s = 0.0f;
#pragma unroll
  for (int e = 0; e < 8; ++e) {
    const float ex = __expf(v[e] - m);       // v==-1e30 -> 0
    v[e] = (base + e < L) ? ex : 0.0f;
    s += v[e];
  }
#pragma unroll
  for (int o = 32; o > 0; o >>= 1) s += __shfl_xor(s, o, 64);
  if (lane == 0) reds[wave] = s;
  __syncthreads();
  s = reds[0] + reds[1] + reds[2] + reds[3];
  const float inv = 1.0f / s;

  if (base < Lw) {
    u16x8 o8;
#pragma unroll
    for (int e = 0; e < 8; ++e) o8[e] = f2bf(v[e] * inv);
    *(u16x8*)(p + base) = o8;
  }
}

extern "C" void kernel_launch(void* const* d_in, const int* in_sizes, int n_in,
                              void* d_out, int out_size, void* d_ws, size_t ws_size,
                              hipStream_t stream)
{
  (void)in_sizes; (void)n_in; (void)out_size; (void)ws_size;
  const int B = 8, T = 2048, C = 1024;
  const int M = B * T;        // 16384
  const int C3 = 3 * C;       // 3072

  // inputs AND output are FP32 (reference dtypes)
  const float* x     = (const float*)d_in[0];
  const float* Wkqv  = (const float*)d_in[1];
  const float* bkqv  = (const float*)d_in[2];
  const float* Wproj = (const float*)d_in[3];
  const float* bproj = (const float*)d_in[4];
  float* out = (float*)d_out;

  // Workspace: 232 MiB footprint. xb dead after GEMM1; ao aliases it.
  char* w = (char*)d_ws;
  u16* xb     = (u16*)w; w += (size_t)M * C * 2;        // 33.5 MB [M][C]  (aliased by ao)
  u16* WkqvT  = (u16*)w; w += (size_t)C3 * C * 2;       //  6.3 MB [3C][C]
  u16* WprojT = (u16*)w; w += (size_t)C * C * 2;        //  2.1 MB [C][C]
  u16* kqv    = (u16*)w; w += (size_t)M * C3 * 2;       // 100.7 MB [M][3C] (v third unused)
  u16* vT     = (u16*)w; w += (size_t)B * C * T * 2;    // 33.5 MB [B][C][T]
  u16* sc     = (u16*)w; w += (size_t)B * T * T * 2;    // 67.1 MB [B][T][T]
  u16* ao     = xb;                                     // alias: lifetimes disjoint

  dim3 tb(32, 8);

  // x -> bf16
  f32_to_bf16<<<(M * C) / 1024, 256, 0, stream>>>(x, xb);

  // weights -> bf16, NT layout
  transpose_f2b<<<dim3(C3 / 32, C / 32, 1), tb, 0, stream>>>(Wkqv, C3, WkqvT, C);
  transpose_f2b<<<dim3(C / 32, C / 32, 1), tb, 0, stream>>>(Wproj, C, WprojT, C);

  // kqv = x @ W_kqv + b_kqv  [M][3C]. mode 3: N fastest -> A-tile L2 reuse;
  // T1 swizzle gives each XCD 8 M-rows x all 12 N (A set = 4 MB = one L2).
  // V third is written TRANSPOSED directly into vT (fused epilogue).
  gemm_nt<u16><<<dim3(C3 / BN, M / BM, 1), 512, 0, stream>>>(
      xb, C, 0, WkqvT, C, 0, kqv, C3, 0, C, bkqv, 1.0f, 3, vT);

  // scores = q @ k^T * (1/sqrt(T)), lower-triangular tiles only
  // (T1 swizzle chunk = 64 blocks = exactly one batch per XCD)
  gemm_nt<u16><<<dim3(T / BM, T / BN, B), 512, 0, stream>>>(
      kqv + C, C3, (long long)T * C3, kqv, C3, (long long)T * C3,
      sc, T, (long long)T * T, C, nullptr, 0.022097086912079608f, 1, nullptr);

  // causal softmax in place
  softmax_causal<<<B * T, 256, 0, stream>>>(sc, T);

  // ao = probs @ v  (NT against vT), K trimmed per tile row; ao aliases xb
  // (T1 swizzle chunk = 32 blocks = one batch per XCD)
  gemm_nt<u16><<<dim3(T / BM, C / BN, B), 512, 0, stream>>>(
      sc, T, (long long)T * T, vT, T, (long long)C * T,
      ao, C, (long long)T * C, T, nullptr, 1.0f, 2, nullptr);

  // out = ao @ W_proj + b_proj   -- FP32 output. mode 3 (grid x=N fastest)
  // so the 4 N-blocks sharing an A-tile are adjacent -> same XCD after T1.
  gemm_nt<float><<<dim3(C / BN, M / BM, 1), 512, 0, stream>>>(
      ao, C, 0, WprojT, C, 0, out, C, 0, C, bproj, 1.0f, 3, nullptr);
}